// Round 6
// baseline (641.745 us; speedup 1.0000x reference)
//
#include <hip/hip_runtime.h>
#include <hip/hip_bf16.h>
#include <math.h>

// GATv2 3-layer GNN, MI355X. CSR-by-dst + fused online-softmax aggregation.
// R2: parallel pooling. R3: register-tiled fp32 linear.
// R5: layer-1 fully-fused kernel (W in registers, 8-dim aggregation) — avoids
//     the 8xXCD L2-replication fetch of the 25.6MB xl buffer (K=8 only).
//     Layers 2-3 keep the R4 fused body (measured floor ~200MB fetch @2.8TB/s).

__device__ __forceinline__ float lrelu(float x) { return x > 0.f ? x : 0.2f * x; }
__device__ __forceinline__ float elu1(float x) { return x > 0.f ? x : expm1f(x); }

__device__ __forceinline__ unsigned f2ord(float x) {
    unsigned b = __float_as_uint(x);
    return (b & 0x80000000u) ? ~b : (b | 0x80000000u);
}
__device__ __forceinline__ float ord2f(unsigned u) {
    unsigned b = (u & 0x80000000u) ? (u & 0x7FFFFFFFu) : ~u;
    return __uint_as_float(b);
}

// ---------------- CSR build ----------------
__global__ void k_zero_i32(int* __restrict__ p, int n) {
    int i = blockIdx.x * blockDim.x + threadIdx.x;
    if (i < n) p[i] = 0;
}

__global__ void k_hist(const int* __restrict__ ei, int E, int N, int* __restrict__ deg) {
    int e = blockIdx.x * blockDim.x + threadIdx.x;
    int Etot = E + N;
    if (e >= Etot) return;
    int d = (e < E) ? ei[E + e] : (e - E);
    atomicAdd(&deg[d], 1);
}

__global__ void __launch_bounds__(1024) k_scan(const int* __restrict__ deg, int n,
                                               int* __restrict__ row_off, int* __restrict__ cursor) {
    __shared__ int wsum[16];
    __shared__ int sbase;
    int tid = threadIdx.x;
    int lane = tid & 63, w = tid >> 6;
    if (tid == 0) sbase = 0;
    __syncthreads();
    for (int start = 0; start < n; start += 1024) {
        int i = start + tid;
        int v = (i < n) ? deg[i] : 0;
        int s = v;
        #pragma unroll
        for (int d = 1; d < 64; d <<= 1) {
            int t = __shfl_up(s, d, 64);
            if (lane >= d) s += t;
        }
        if (lane == 63) wsum[w] = s;
        __syncthreads();
        int wbase = 0;
        for (int k = 0; k < w; k++) wbase += wsum[k];
        int excl = sbase + wbase + (s - v);
        if (i < n) { row_off[i] = excl; cursor[i] = excl; }
        __syncthreads();
        if (tid == 1023) sbase = excl + v;
        __syncthreads();
    }
    if (tid == 0) row_off[n] = sbase;
}

__global__ void k_scatter(const int* __restrict__ ei, int E, int N,
                          int* __restrict__ cursor,
                          int* __restrict__ csr_src) {
    int e = blockIdx.x * blockDim.x + threadIdx.x;
    int Etot = E + N;
    if (e >= Etot) return;
    int s, d;
    if (e < E) { s = ei[e]; d = ei[E + e]; } else { s = e - E; d = e - E; }
    int p = atomicAdd(&cursor[d], 1);
    csr_src[p] = s;
}

// ---------------- layer-1 fully fused: linear(K=8) + attention + aggregate ----
// wave per dst node; 4 slots x 16 lanes; Wl (8x8 per lane) in registers.
// Aggregates in 8-dim input space, projects once per node at the end.
__global__ void __launch_bounds__(256) k_fused1(
        const int* __restrict__ row_off, const int* __restrict__ csr_src,
        const float* __restrict__ x,                         // [N,8]
        const float* __restrict__ Wl, const float* __restrict__ bl,   // 8x128,128
        const float* __restrict__ Wr, const float* __restrict__ br,
        const float* __restrict__ att,                       // 128
        const float* __restrict__ bias,                      // 128
        float* __restrict__ hout, int N) {
    int wid = (blockIdx.x * blockDim.x + threadIdx.x) >> 6;
    int lane = threadIdx.x & 63;
    if (wid >= N) return;
    int slot = lane >> 4;
    int j = lane & 15;
    int c0 = j * 8;

    // per-lane weight registers: Wl columns c0..c0+7 for all 8 k
    float wl[8][8];
    #pragma unroll
    for (int k = 0; k < 8; k++) {
        float4 a = *(const float4*)(Wl + k * 128 + c0);
        float4 b = *(const float4*)(Wl + k * 128 + c0 + 4);
        wl[k][0] = a.x; wl[k][1] = a.y; wl[k][2] = a.z; wl[k][3] = a.w;
        wl[k][4] = b.x; wl[k][5] = b.y; wl[k][6] = b.z; wl[k][7] = b.w;
    }
    float blv[8], attv[8];
    {
        float4 a = *(const float4*)(bl + c0), b = *(const float4*)(bl + c0 + 4);
        blv[0] = a.x; blv[1] = a.y; blv[2] = a.z; blv[3] = a.w;
        blv[4] = b.x; blv[5] = b.y; blv[6] = b.z; blv[7] = b.w;
        float4 c = *(const float4*)(att + c0), d = *(const float4*)(att + c0 + 4);
        attv[0] = c.x; attv[1] = c.y; attv[2] = c.z; attv[3] = c.w;
        attv[4] = d.x; attv[5] = d.y; attv[6] = d.z; attv[7] = d.w;
    }
    // xr row (this dst's target transform), computed once
    float xrv[8];
    {
        float4 d0 = *(const float4*)(x + (size_t)wid * 8);
        float4 d1 = *(const float4*)(x + (size_t)wid * 8 + 4);
        float xd[8] = {d0.x, d0.y, d0.z, d0.w, d1.x, d1.y, d1.z, d1.w};
        float4 r0 = *(const float4*)(br + c0), r1 = *(const float4*)(br + c0 + 4);
        xrv[0] = r0.x; xrv[1] = r0.y; xrv[2] = r0.z; xrv[3] = r0.w;
        xrv[4] = r1.x; xrv[5] = r1.y; xrv[6] = r1.z; xrv[7] = r1.w;
        #pragma unroll
        for (int k = 0; k < 8; k++) {
            float4 a = *(const float4*)(Wr + k * 128 + c0);
            float4 b = *(const float4*)(Wr + k * 128 + c0 + 4);
            xrv[0] = fmaf(xd[k], a.x, xrv[0]); xrv[1] = fmaf(xd[k], a.y, xrv[1]);
            xrv[2] = fmaf(xd[k], a.z, xrv[2]); xrv[3] = fmaf(xd[k], a.w, xrv[3]);
            xrv[4] = fmaf(xd[k], b.x, xrv[4]); xrv[5] = fmaf(xd[k], b.y, xrv[5]);
            xrv[6] = fmaf(xd[k], b.z, xrv[6]); xrv[7] = fmaf(xd[k], b.w, xrv[7]);
        }
    }

    int p0 = row_off[wid], p1 = row_off[wid + 1];
    float m = -INFINITY, den = 0.f;
    float acc[8];
    #pragma unroll
    for (int k = 0; k < 8; k++) acc[k] = 0.f;

    int p = p0 + slot;
    int s = (p < p1) ? csr_src[p] : 0;
    while (p < p1) {
        int pn = p + 4;
        int sn = (pn < p1) ? csr_src[pn] : 0;
        float4 a = *(const float4*)(x + (size_t)s * 8);
        float4 b = *(const float4*)(x + (size_t)s * 8 + 4);
        float xs_[8] = {a.x, a.y, a.z, a.w, b.x, b.y, b.z, b.w};
        // score: att . lrelu(xl + xr), xl recomputed from 8-dim input
        float sc = 0.f;
        #pragma unroll
        for (int q = 0; q < 8; q++) {
            float v = blv[q];
            #pragma unroll
            for (int k = 0; k < 8; k++) v = fmaf(xs_[k], wl[k][q], v);
            float t = v + xrv[q];
            sc = fmaf(fmaxf(t, 0.2f * t), attv[q], sc);
        }
        sc += __shfl_xor(sc, 1, 64);
        sc += __shfl_xor(sc, 2, 64);
        sc += __shfl_xor(sc, 4, 64);   // head = 8 lanes (C=64, 8 cols/lane)
        // online softmax; aggregate in 8-dim input space
        float mnew = fmaxf(m, sc);
        float corr = __expf(m - mnew);
        float ex = __expf(sc - mnew);
        den = den * corr + ex;
        #pragma unroll
        for (int k = 0; k < 8; k++) acc[k] = fmaf(ex, xs_[k], acc[k] * corr);
        m = mnew;
        p = pn; s = sn;
    }
    // combine 4 slots
    float mAll = fmaxf(m, __shfl_xor(m, 16, 64));
    mAll = fmaxf(mAll, __shfl_xor(mAll, 32, 64));
    float scale = __expf(m - mAll);
    float dtot = den * scale;
    dtot += __shfl_xor(dtot, 16, 64);
    dtot += __shfl_xor(dtot, 32, 64);
    #pragma unroll
    for (int k = 0; k < 8; k++) {
        float a2 = acc[k] * scale;
        a2 += __shfl_xor(a2, 16, 64);
        a2 += __shfl_xor(a2, 32, 64);
        acc[k] = a2;
    }
    if (slot == 0) {
        float inv = 1.0f / (dtot + 1e-16f);
        #pragma unroll
        for (int q = 0; q < 8; q++) {
            float v = blv[q];
            #pragma unroll
            for (int k = 0; k < 8; k++) v = fmaf(acc[k] * inv, wl[k][q], v);
            v += bias[c0 + q];
            hout[(size_t)wid * 128 + c0 + q] = elu1(v);
        }
    }
}

// ---------------- register-tiled dual linear (layer 2: 128->128) ----------
template <int K, int MH>
__global__ void k_linear2(const float* __restrict__ x, int N,
                          const float* __restrict__ Wl, const float* __restrict__ bl,
                          const float* __restrict__ Wr, const float* __restrict__ br,
                          float* __restrict__ xl, float* __restrict__ xr) {
    constexpr int NCG = MH / 2;
    __shared__ float xs[32 * K];
    int tid = threadIdx.x;
    int node0 = blockIdx.x * 32;
    for (int idx = tid * 4; idx < 32 * K; idx += NCG * 4 * 4) {
        int node = node0 + idx / K;
        float4 v = make_float4(0.f, 0.f, 0.f, 0.f);
        if (node < N) v = *(const float4*)(x + (size_t)node0 * K + idx);
        *(float4*)(xs + idx) = v;
    }
    __syncthreads();

    int cg = tid % NCG;
    int ng = tid / NCG;
    bool rightSide = cg >= (MH / 4);
    int c = (rightSide ? cg - MH / 4 : cg) * 4;
    const float* W  = rightSide ? Wr : Wl;
    const float* bb = rightSide ? br : bl;
    float* out      = rightSide ? xr : xl;

    float acc[8][4];
    #pragma unroll
    for (int i = 0; i < 8; i++)
        #pragma unroll
        for (int j = 0; j < 4; j++) acc[i][j] = 0.f;

    const float* xrow = xs + ng * 8 * K;
    for (int k0 = 0; k0 < K; k0 += 4) {
        float4 wv[4];
        #pragma unroll
        for (int kk = 0; kk < 4; kk++)
            wv[kk] = *(const float4*)(W + (size_t)(k0 + kk) * MH + c);
        #pragma unroll
        for (int i = 0; i < 8; i++) {
            float4 xv = *(const float4*)(xrow + i * K + k0);
            float xvk[4] = {xv.x, xv.y, xv.z, xv.w};
            #pragma unroll
            for (int kk = 0; kk < 4; kk++) {
                acc[i][0] += xvk[kk] * wv[kk].x;
                acc[i][1] += xvk[kk] * wv[kk].y;
                acc[i][2] += xvk[kk] * wv[kk].z;
                acc[i][3] += xvk[kk] * wv[kk].w;
            }
        }
    }
    float4 bv = *(const float4*)(bb + c);
    #pragma unroll
    for (int i = 0; i < 8; i++) {
        int node = node0 + ng * 8 + i;
        if (node < N) {
            float4 o = make_float4(acc[i][0] + bv.x, acc[i][1] + bv.y,
                                   acc[i][2] + bv.z, acc[i][3] + bv.w);
            *(float4*)(out + (size_t)node * MH + c) = o;
        }
    }
}

// ---------------- layer-3 linear (128->32), 256-thread blocks ----------------
__global__ void __launch_bounds__(256) k_linear3(
        const float* __restrict__ x, int N,
        const float* __restrict__ Wl, const float* __restrict__ bl,
        const float* __restrict__ Wr, const float* __restrict__ br,
        float* __restrict__ xl, float* __restrict__ xr) {
    __shared__ float xs[32 * 128];
    int tid = threadIdx.x;
    int node0 = blockIdx.x * 32;
    for (int idx = tid * 4; idx < 32 * 128; idx += 256 * 4) {
        int node = node0 + idx / 128;
        float4 v = make_float4(0.f, 0.f, 0.f, 0.f);
        if (node < N) v = *(const float4*)(x + (size_t)node0 * 128 + idx);
        *(float4*)(xs + idx) = v;
    }
    __syncthreads();
    int cg = tid & 15, ng = tid >> 4;      // 16 col-groups x 16 node-groups(2 nodes)
    bool rightSide = cg >= 8;
    int c = (rightSide ? cg - 8 : cg) * 4;
    const float* W  = rightSide ? Wr : Wl;
    const float* bb = rightSide ? br : bl;
    float* out      = rightSide ? xr : xl;

    float acc[2][4];
    #pragma unroll
    for (int i = 0; i < 2; i++)
        #pragma unroll
        for (int j = 0; j < 4; j++) acc[i][j] = 0.f;

    const float* xrow = xs + ng * 2 * 128;
    for (int k0 = 0; k0 < 128; k0 += 4) {
        float4 wv[4];
        #pragma unroll
        for (int kk = 0; kk < 4; kk++)
            wv[kk] = *(const float4*)(W + (size_t)(k0 + kk) * 32 + c);
        #pragma unroll
        for (int i = 0; i < 2; i++) {
            float4 xv = *(const float4*)(xrow + i * 128 + k0);
            float xvk[4] = {xv.x, xv.y, xv.z, xv.w};
            #pragma unroll
            for (int kk = 0; kk < 4; kk++) {
                acc[i][0] += xvk[kk] * wv[kk].x;
                acc[i][1] += xvk[kk] * wv[kk].y;
                acc[i][2] += xvk[kk] * wv[kk].z;
                acc[i][3] += xvk[kk] * wv[kk].w;
            }
        }
    }
    float4 bv = *(const float4*)(bb + c);
    #pragma unroll
    for (int i = 0; i < 2; i++) {
        int node = node0 + ng * 2 + i;
        if (node < N) {
            float4 o = make_float4(acc[i][0] + bv.x, acc[i][1] + bv.y,
                                   acc[i][2] + bv.z, acc[i][3] + bv.w);
            *(float4*)(out + (size_t)node * 32 + c) = o;
        }
    }
}

// ---------------- fused online-softmax attention + aggregate (R4 body) -------
template <int CPL>
__device__ __forceinline__ void loadrow(const float* __restrict__ p, float* v) {
    if constexpr (CPL == 8) {
        float4 a = ((const float4*)p)[0];
        float4 b = ((const float4*)p)[1];
        v[0] = a.x; v[1] = a.y; v[2] = a.z; v[3] = a.w;
        v[4] = b.x; v[5] = b.y; v[6] = b.z; v[7] = b.w;
    } else {
        float2 a = ((const float2*)p)[0];
        v[0] = a.x; v[1] = a.y;
    }
}

template <int HC, int C>
__global__ void k_fused(const int* __restrict__ row_off, const int* __restrict__ csr_src,
                        const float* __restrict__ xl, const float* __restrict__ xr,
                        const float* __restrict__ att, const float* __restrict__ bias,
                        float* __restrict__ hout, int N) {
    constexpr int CPL = HC / 16;
    constexpr int GROUP = (16 * C) / HC;
    int wid = (blockIdx.x * blockDim.x + threadIdx.x) >> 6;
    int lane = threadIdx.x & 63;
    if (wid >= N) return;
    int slot = lane >> 4;
    int j = lane & 15;
    int c0 = j * CPL;

    int p0 = row_off[wid], p1 = row_off[wid + 1];

    float xrv[CPL], attv[CPL];
    loadrow<CPL>(xr + (size_t)wid * HC + c0, xrv);
    loadrow<CPL>(att + c0, attv);

    float m = -INFINITY, den = 0.f;
    float acc[CPL];
    #pragma unroll
    for (int q = 0; q < CPL; q++) acc[q] = 0.f;

    int p = p0 + slot;
    int s = (p < p1) ? csr_src[p] : 0;
    while (p < p1) {
        int pn = p + 4;
        int sn = (pn < p1) ? csr_src[pn] : 0;
        float xlv[CPL];
        loadrow<CPL>(xl + (size_t)s * HC + c0, xlv);
        float part = 0.f;
        #pragma unroll
        for (int q = 0; q < CPL; q++) part += lrelu(xlv[q] + xrv[q]) * attv[q];
        #pragma unroll
        for (int msk = 1; msk < GROUP; msk <<= 1) part += __shfl_xor(part, msk, 64);
        float mnew = fmaxf(m, part);
        float corr = __expf(m - mnew);
        float ex = __expf(part - mnew);
        den = den * corr + ex;
        #pragma unroll
        for (int q = 0; q < CPL; q++) acc[q] = acc[q] * corr + ex * xlv[q];
        m = mnew;
        p = pn; s = sn;
    }
    float mAll = fmaxf(m, __shfl_xor(m, 16, 64));
    mAll = fmaxf(mAll, __shfl_xor(mAll, 32, 64));
    float scale = __expf(m - mAll);
    float dtot = den * scale;
    dtot += __shfl_xor(dtot, 16, 64);
    dtot += __shfl_xor(dtot, 32, 64);
    #pragma unroll
    for (int q = 0; q < CPL; q++) {
        float a = acc[q] * scale;
        a += __shfl_xor(a, 16, 64);
        a += __shfl_xor(a, 32, 64);
        acc[q] = a;
    }
    if (slot == 0) {
        float inv = 1.0f / (dtot + 1e-16f);
        #pragma unroll
        for (int q = 0; q < CPL; q++) {
            float v = acc[q] * inv + bias[c0 + q];
            hout[(size_t)wid * HC + c0 + q] = elu1(v);
        }
    }
}

// ---------------- graph pooling (parallel, 2-stage) ----------------
__global__ void __launch_bounds__(256) k_pool_partial(
        const float* __restrict__ h, const int* __restrict__ batch, int N, int G,
        float* __restrict__ gsum, unsigned* __restrict__ gmax) {
    __shared__ float lsum[512];
    __shared__ unsigned lmax[512];
    int tid = threadIdx.x;
    for (int i = tid; i < G * 32; i += 256) { lsum[i] = 0.f; lmax[i] = 0u; }
    __syncthreads();
    int chunk = (N + gridDim.x - 1) / gridDim.x;
    int start = blockIdx.x * chunk;
    int end = min(N, start + chunk);
    int col = tid & 31, row = tid >> 5;
    int gc = -1; float ps = 0.f; unsigned pm = 0u;
    for (int i = start + row; i < end; i += 8) {
        int g = batch[i];
        if (g != gc) {
            if (gc >= 0) { atomicAdd(&lsum[gc * 32 + col], ps); atomicMax(&lmax[gc * 32 + col], pm); }
            gc = g; ps = 0.f; pm = 0u;
        }
        float v = h[(size_t)i * 32 + col];
        ps += v; pm = max(pm, f2ord(v));
    }
    if (gc >= 0) { atomicAdd(&lsum[gc * 32 + col], ps); atomicMax(&lmax[gc * 32 + col], pm); }
    __syncthreads();
    for (int i = tid; i < G * 32; i += 256) {
        if (lmax[i]) {
            atomicAdd(&gsum[i], lsum[i]);
            atomicMax(&gmax[i], lmax[i]);
        }
    }
}

__global__ void k_pool_final(const float* __restrict__ gsum, const unsigned* __restrict__ gmax,
                             const int* __restrict__ batch, int N, float* __restrict__ out) {
    int g = blockIdx.x;
    int t = threadIdx.x;
    __shared__ int s_cnt;
    if (t == 0) {
        int lo = 0, hi = N;
        while (lo < hi) { int m = (lo + hi) >> 1; if (batch[m] < g) lo = m + 1; else hi = m; }
        int a = lo;
        lo = a; hi = N;
        while (lo < hi) { int m = (lo + hi) >> 1; if (batch[m] < g + 1) lo = m + 1; else hi = m; }
        s_cnt = lo - a;
    }
    __syncthreads();
    if (t < 32) {
        out[g * 64 + t] = gsum[g * 32 + t] / (float)max(s_cnt, 1);
    } else {
        out[g * 64 + t] = ord2f(gmax[g * 32 + (t - 32)]);
    }
}

extern "C" void kernel_launch(void* const* d_in, const int* in_sizes, int n_in,
                              void* d_out, int out_size, void* d_ws, size_t ws_size,
                              hipStream_t stream) {
    const float* x      = (const float*)d_in[0];
    const int*   ei     = (const int*)d_in[1];
    const int*   batch  = (const int*)d_in[2];
    const float* Wl1 = (const float*)d_in[3],  *bl1 = (const float*)d_in[4];
    const float* Wr1 = (const float*)d_in[5],  *br1 = (const float*)d_in[6];
    const float* att1= (const float*)d_in[7],  *b1  = (const float*)d_in[8];
    const float* Wl2 = (const float*)d_in[9],  *bl2 = (const float*)d_in[10];
    const float* Wr2 = (const float*)d_in[11], *br2 = (const float*)d_in[12];
    const float* att2= (const float*)d_in[13], *b2  = (const float*)d_in[14];
    const float* Wl3 = (const float*)d_in[15], *bl3 = (const float*)d_in[16];
    const float* Wr3 = (const float*)d_in[17], *br3 = (const float*)d_in[18];
    const float* att3= (const float*)d_in[19], *b3  = (const float*)d_in[20];

    int N = in_sizes[0] / 8;
    int E = in_sizes[1] / 2;
    int G = out_size / 64;
    int Etot = E + N;

    char* w = (char*)d_ws;
    auto carve = [&](size_t bytes) {
        void* p = (void*)w;
        w += (bytes + 255) & ~(size_t)255;
        return p;
    };
    int*      deg     = (int*)carve((size_t)N * 4);
    int*      row_off = (int*)carve((size_t)(N + 1) * 4);
    int*      cursor  = (int*)carve((size_t)N * 4);
    int*      csr_src = (int*)carve((size_t)Etot * 4);
    float*    gsum    = (float*)carve((size_t)G * 32 * 4);
    unsigned* gmax    = (unsigned*)carve((size_t)G * 32 * 4);
    float*    bufA    = (float*)carve((size_t)N * 128 * 4);  // xl
    float*    bufB    = (float*)carve((size_t)N * 128 * 4);  // xr
    float*    bufC    = (float*)carve((size_t)N * 128 * 4);  // h (layer outputs)
    (void)ws_size; (void)n_in;

    // ---- CSR by dst (incl. self loops) + pool accumulator init ----
    k_zero_i32<<<(N + 255) / 256, 256, 0, stream>>>(deg, N);
    k_zero_i32<<<(2 * G * 32 + 255) / 256, 256, 0, stream>>>((int*)gsum, 2 * G * 32);
    k_hist<<<(Etot + 255) / 256, 256, 0, stream>>>(ei, E, N, deg);
    k_scan<<<1, 1024, 0, stream>>>(deg, N, row_off, cursor);
    k_scatter<<<(Etot + 255) / 256, 256, 0, stream>>>(ei, E, N, cursor, csr_src);

    int grdLin = (N + 31) / 32;
    int grdFused = (N + 3) / 4;

    // ---- Layer 1: fully fused (no xl/xr materialization) ----
    k_fused1<<<grdFused, 256, 0, stream>>>(row_off, csr_src, x,
                                           Wl1, bl1, Wr1, br1, att1, b1, bufC, N);

    // ---- Layer 2: 128 -> 128 ----
    k_linear2<128, 128><<<grdLin, 256, 0, stream>>>(bufC, N, Wl2, bl2, Wr2, br2, bufA, bufB);
    k_fused<128, 64><<<grdFused, 256, 0, stream>>>(row_off, csr_src, bufA, bufB, att2, b2, bufC, N);

    // ---- Layer 3: 128 -> 32 (H=1,C=32) ----
    k_linear3<<<grdLin, 256, 0, stream>>>(bufC, N, Wl3, bl3, Wr3, br3, bufA, bufB);
    k_fused<32, 32><<<grdFused, 256, 0, stream>>>(row_off, csr_src, bufA, bufB, att3, b3, bufC, N);

    // ---- pooling ----
    k_pool_partial<<<256, 256, 0, stream>>>(bufC, batch, N, G, gsum, gmax);
    k_pool_final<<<G, 64, 0, stream>>>(gsum, gmax, batch, N, (float*)d_out);
}

// Round 7
// 583.088 us; speedup vs baseline: 1.1006x; 1.1006x over previous
//
#include <hip/hip_runtime.h>
#include <hip/hip_bf16.h>
#include <math.h>

// GATv2 3-layer GNN, MI355X. CSR-by-dst + fused online-softmax aggregation.
// R3: register-tiled fp32 linear. R4: best-known fused body (36 VGPR, occ 63%).
// R5 lesson: HC=128 fused layers are fetch-path bound (~200MB @2.8TB/s floor);
//            recompute-instead-of-gather loses badly. Layer 1 reverted here.
// R6: single-kernel pooling (last-block-done), merged init, 256-thread lin3.

__device__ __forceinline__ float lrelu(float x) { return x > 0.f ? x : 0.2f * x; }
__device__ __forceinline__ float elu1(float x) { return x > 0.f ? x : expm1f(x); }

__device__ __forceinline__ unsigned f2ord(float x) {
    unsigned b = __float_as_uint(x);
    return (b & 0x80000000u) ? ~b : (b | 0x80000000u);
}
__device__ __forceinline__ float ord2f(unsigned u) {
    unsigned b = (u & 0x80000000u) ? (u & 0x7FFFFFFFu) : ~u;
    return __uint_as_float(b);
}

// ---------------- init: deg=0, gsum/gmax=0, done=0 ----------------
__global__ void k_init(int* __restrict__ deg, int N, int* __restrict__ pool_acc, int PA) {
    int i = blockIdx.x * blockDim.x + threadIdx.x;
    int stride = gridDim.x * blockDim.x;
    for (int k = i; k < N; k += stride) deg[k] = 0;
    for (int k = i; k < PA; k += stride) pool_acc[k] = 0;
}

__global__ void k_hist(const int* __restrict__ ei, int E, int N, int* __restrict__ deg) {
    int e = blockIdx.x * blockDim.x + threadIdx.x;
    int Etot = E + N;
    if (e >= Etot) return;
    int d = (e < E) ? ei[E + e] : (e - E);
    atomicAdd(&deg[d], 1);
}

__global__ void __launch_bounds__(1024) k_scan(const int* __restrict__ deg, int n,
                                               int* __restrict__ row_off, int* __restrict__ cursor) {
    __shared__ int wsum[16];
    __shared__ int sbase;
    int tid = threadIdx.x;
    int lane = tid & 63, w = tid >> 6;
    if (tid == 0) sbase = 0;
    __syncthreads();
    for (int start = 0; start < n; start += 1024) {
        int i = start + tid;
        int v = (i < n) ? deg[i] : 0;
        int s = v;
        #pragma unroll
        for (int d = 1; d < 64; d <<= 1) {
            int t = __shfl_up(s, d, 64);
            if (lane >= d) s += t;
        }
        if (lane == 63) wsum[w] = s;
        __syncthreads();
        int wbase = 0;
        for (int k = 0; k < w; k++) wbase += wsum[k];
        int excl = sbase + wbase + (s - v);
        if (i < n) { row_off[i] = excl; cursor[i] = excl; }
        __syncthreads();
        if (tid == 1023) sbase = excl + v;
        __syncthreads();
    }
    if (tid == 0) row_off[n] = sbase;
}

__global__ void k_scatter(const int* __restrict__ ei, int E, int N,
                          int* __restrict__ cursor,
                          int* __restrict__ csr_src) {
    int e = blockIdx.x * blockDim.x + threadIdx.x;
    int Etot = E + N;
    if (e >= Etot) return;
    int s, d;
    if (e < E) { s = ei[e]; d = ei[E + e]; } else { s = e - E; d = e - E; }
    int p = atomicAdd(&cursor[d], 1);
    csr_src[p] = s;
}

// ---------------- register-tiled dual linear (layers 1,2) ----------------
template <int K, int MH>
__global__ void k_linear2(const float* __restrict__ x, int N,
                          const float* __restrict__ Wl, const float* __restrict__ bl,
                          const float* __restrict__ Wr, const float* __restrict__ br,
                          float* __restrict__ xl, float* __restrict__ xr) {
    constexpr int NCG = MH / 2;
    __shared__ float xs[32 * K];
    int tid = threadIdx.x;
    int node0 = blockIdx.x * 32;
    for (int idx = tid * 4; idx < 32 * K; idx += NCG * 4 * 4) {
        int node = node0 + idx / K;
        float4 v = make_float4(0.f, 0.f, 0.f, 0.f);
        if (node < N) v = *(const float4*)(x + (size_t)node0 * K + idx);
        *(float4*)(xs + idx) = v;
    }
    __syncthreads();

    int cg = tid % NCG;
    int ng = tid / NCG;
    bool rightSide = cg >= (MH / 4);
    int c = (rightSide ? cg - MH / 4 : cg) * 4;
    const float* W  = rightSide ? Wr : Wl;
    const float* bb = rightSide ? br : bl;
    float* out      = rightSide ? xr : xl;

    float acc[8][4];
    #pragma unroll
    for (int i = 0; i < 8; i++)
        #pragma unroll
        for (int j = 0; j < 4; j++) acc[i][j] = 0.f;

    const float* xrow = xs + ng * 8 * K;
    for (int k0 = 0; k0 < K; k0 += 4) {
        float4 wv[4];
        #pragma unroll
        for (int kk = 0; kk < 4; kk++)
            wv[kk] = *(const float4*)(W + (size_t)(k0 + kk) * MH + c);
        #pragma unroll
        for (int i = 0; i < 8; i++) {
            float4 xv = *(const float4*)(xrow + i * K + k0);
            float xvk[4] = {xv.x, xv.y, xv.z, xv.w};
            #pragma unroll
            for (int kk = 0; kk < 4; kk++) {
                acc[i][0] += xvk[kk] * wv[kk].x;
                acc[i][1] += xvk[kk] * wv[kk].y;
                acc[i][2] += xvk[kk] * wv[kk].z;
                acc[i][3] += xvk[kk] * wv[kk].w;
            }
        }
    }
    float4 bv = *(const float4*)(bb + c);
    #pragma unroll
    for (int i = 0; i < 8; i++) {
        int node = node0 + ng * 8 + i;
        if (node < N) {
            float4 o = make_float4(acc[i][0] + bv.x, acc[i][1] + bv.y,
                                   acc[i][2] + bv.z, acc[i][3] + bv.w);
            *(float4*)(out + (size_t)node * MH + c) = o;
        }
    }
}

// ---------------- layer-3 linear (128->32), 256-thread blocks ----------------
__global__ void __launch_bounds__(256) k_linear3(
        const float* __restrict__ x, int N,
        const float* __restrict__ Wl, const float* __restrict__ bl,
        const float* __restrict__ Wr, const float* __restrict__ br,
        float* __restrict__ xl, float* __restrict__ xr) {
    __shared__ float xs[32 * 128];
    int tid = threadIdx.x;
    int node0 = blockIdx.x * 32;
    for (int idx = tid * 4; idx < 32 * 128; idx += 256 * 4) {
        int node = node0 + idx / 128;
        float4 v = make_float4(0.f, 0.f, 0.f, 0.f);
        if (node < N) v = *(const float4*)(x + (size_t)node0 * 128 + idx);
        *(float4*)(xs + idx) = v;
    }
    __syncthreads();
    int cg = tid & 15, ng = tid >> 4;   // 16 col-groups x 16 node-groups(2 nodes)
    bool rightSide = cg >= 8;
    int c = (rightSide ? cg - 8 : cg) * 4;
    const float* W  = rightSide ? Wr : Wl;
    const float* bb = rightSide ? br : bl;
    float* out      = rightSide ? xr : xl;

    float acc[2][4];
    #pragma unroll
    for (int i = 0; i < 2; i++)
        #pragma unroll
        for (int j = 0; j < 4; j++) acc[i][j] = 0.f;

    const float* xrow = xs + ng * 2 * 128;
    for (int k0 = 0; k0 < 128; k0 += 4) {
        float4 wv[4];
        #pragma unroll
        for (int kk = 0; kk < 4; kk++)
            wv[kk] = *(const float4*)(W + (size_t)(k0 + kk) * 32 + c);
        #pragma unroll
        for (int i = 0; i < 2; i++) {
            float4 xv = *(const float4*)(xrow + i * 128 + k0);
            float xvk[4] = {xv.x, xv.y, xv.z, xv.w};
            #pragma unroll
            for (int kk = 0; kk < 4; kk++) {
                acc[i][0] += xvk[kk] * wv[kk].x;
                acc[i][1] += xvk[kk] * wv[kk].y;
                acc[i][2] += xvk[kk] * wv[kk].z;
                acc[i][3] += xvk[kk] * wv[kk].w;
            }
        }
    }
    float4 bv = *(const float4*)(bb + c);
    #pragma unroll
    for (int i = 0; i < 2; i++) {
        int node = node0 + ng * 2 + i;
        if (node < N) {
            float4 o = make_float4(acc[i][0] + bv.x, acc[i][1] + bv.y,
                                   acc[i][2] + bv.z, acc[i][3] + bv.w);
            *(float4*)(out + (size_t)node * 32 + c) = o;
        }
    }
}

// ---------------- fused online-softmax attention + aggregate (R4 body) -------
template <int CPL>
__device__ __forceinline__ void loadrow(const float* __restrict__ p, float* v) {
    if constexpr (CPL == 8) {
        float4 a = ((const float4*)p)[0];
        float4 b = ((const float4*)p)[1];
        v[0] = a.x; v[1] = a.y; v[2] = a.z; v[3] = a.w;
        v[4] = b.x; v[5] = b.y; v[6] = b.z; v[7] = b.w;
    } else {
        float2 a = ((const float2*)p)[0];
        v[0] = a.x; v[1] = a.y;
    }
}

template <int HC, int C>
__global__ void k_fused(const int* __restrict__ row_off, const int* __restrict__ csr_src,
                        const float* __restrict__ xl, const float* __restrict__ xr,
                        const float* __restrict__ att, const float* __restrict__ bias,
                        float* __restrict__ hout, int N) {
    constexpr int CPL = HC / 16;
    constexpr int GROUP = (16 * C) / HC;
    int wid = (blockIdx.x * blockDim.x + threadIdx.x) >> 6;
    int lane = threadIdx.x & 63;
    if (wid >= N) return;
    int slot = lane >> 4;
    int j = lane & 15;
    int c0 = j * CPL;

    int p0 = row_off[wid], p1 = row_off[wid + 1];

    float xrv[CPL], attv[CPL];
    loadrow<CPL>(xr + (size_t)wid * HC + c0, xrv);
    loadrow<CPL>(att + c0, attv);

    float m = -INFINITY, den = 0.f;
    float acc[CPL];
    #pragma unroll
    for (int q = 0; q < CPL; q++) acc[q] = 0.f;

    int p = p0 + slot;
    int s = (p < p1) ? csr_src[p] : 0;
    while (p < p1) {
        int pn = p + 4;
        int sn = (pn < p1) ? csr_src[pn] : 0;
        float xlv[CPL];
        loadrow<CPL>(xl + (size_t)s * HC + c0, xlv);
        float part = 0.f;
        #pragma unroll
        for (int q = 0; q < CPL; q++) part += lrelu(xlv[q] + xrv[q]) * attv[q];
        #pragma unroll
        for (int msk = 1; msk < GROUP; msk <<= 1) part += __shfl_xor(part, msk, 64);
        float mnew = fmaxf(m, part);
        float corr = __expf(m - mnew);
        float ex = __expf(part - mnew);
        den = den * corr + ex;
        #pragma unroll
        for (int q = 0; q < CPL; q++) acc[q] = acc[q] * corr + ex * xlv[q];
        m = mnew;
        p = pn; s = sn;
    }
    float mAll = fmaxf(m, __shfl_xor(m, 16, 64));
    mAll = fmaxf(mAll, __shfl_xor(mAll, 32, 64));
    float scale = __expf(m - mAll);
    float dtot = den * scale;
    dtot += __shfl_xor(dtot, 16, 64);
    dtot += __shfl_xor(dtot, 32, 64);
    #pragma unroll
    for (int q = 0; q < CPL; q++) {
        float a = acc[q] * scale;
        a += __shfl_xor(a, 16, 64);
        a += __shfl_xor(a, 32, 64);
        acc[q] = a;
    }
    if (slot == 0) {
        float inv = 1.0f / (dtot + 1e-16f);
        #pragma unroll
        for (int q = 0; q < CPL; q++) {
            float v = acc[q] * inv + bias[c0 + q];
            hout[(size_t)wid * HC + c0 + q] = elu1(v);
        }
    }
}

// ---------------- graph pooling: single kernel, last-block finalizes ---------
__global__ void __launch_bounds__(256) k_pool(
        const float* __restrict__ h, const int* __restrict__ batch, int N, int G,
        float* __restrict__ gsum, unsigned* __restrict__ gmax,
        int* __restrict__ done, float* __restrict__ out) {
    __shared__ float lsum[512];
    __shared__ unsigned lmax[512];
    int tid = threadIdx.x;
    for (int i = tid; i < G * 32; i += 256) { lsum[i] = 0.f; lmax[i] = 0u; }
    __syncthreads();
    int chunk = (N + gridDim.x - 1) / gridDim.x;
    int start = blockIdx.x * chunk;
    int end = min(N, start + chunk);
    int col = tid & 31, row = tid >> 5;
    int gc = -1; float ps = 0.f; unsigned pm = 0u;
    for (int i = start + row; i < end; i += 8) {
        int g = batch[i];
        if (g != gc) {
            if (gc >= 0) { atomicAdd(&lsum[gc * 32 + col], ps); atomicMax(&lmax[gc * 32 + col], pm); }
            gc = g; ps = 0.f; pm = 0u;
        }
        float v = h[(size_t)i * 32 + col];
        ps += v; pm = max(pm, f2ord(v));
    }
    if (gc >= 0) { atomicAdd(&lsum[gc * 32 + col], ps); atomicMax(&lmax[gc * 32 + col], pm); }
    __syncthreads();
    for (int i = tid; i < G * 32; i += 256) {
        if (lmax[i]) {
            atomicAdd(&gsum[i], lsum[i]);
            atomicMax(&gmax[i], lmax[i]);
        }
    }
    __threadfence();
    __shared__ int isLast;
    __syncthreads();
    if (tid == 0) isLast = (atomicAdd(done, 1) == (int)gridDim.x - 1);
    __syncthreads();
    if (isLast) {
        for (int i = tid; i < G * 64; i += 256) {
            int g = i >> 6, t = i & 63;
            float val;
            if (t < 32) {
                float s = atomicAdd(&gsum[g * 32 + t], 0.0f);   // coherent read
                int lo = 0, hi = N;
                while (lo < hi) { int mid = (lo + hi) >> 1; if (batch[mid] < g) lo = mid + 1; else hi = mid; }
                int a = lo;
                lo = a; hi = N;
                while (lo < hi) { int mid = (lo + hi) >> 1; if (batch[mid] < g + 1) lo = mid + 1; else hi = mid; }
                int cnt = lo - a;
                val = s / (float)max(cnt, 1);
            } else {
                unsigned u = atomicOr(&gmax[g * 32 + (t - 32)], 0u);  // coherent read
                val = ord2f(u);
            }
            out[i] = val;
        }
    }
}

extern "C" void kernel_launch(void* const* d_in, const int* in_sizes, int n_in,
                              void* d_out, int out_size, void* d_ws, size_t ws_size,
                              hipStream_t stream) {
    const float* x      = (const float*)d_in[0];
    const int*   ei     = (const int*)d_in[1];
    const int*   batch  = (const int*)d_in[2];
    const float* Wl1 = (const float*)d_in[3],  *bl1 = (const float*)d_in[4];
    const float* Wr1 = (const float*)d_in[5],  *br1 = (const float*)d_in[6];
    const float* att1= (const float*)d_in[7],  *b1  = (const float*)d_in[8];
    const float* Wl2 = (const float*)d_in[9],  *bl2 = (const float*)d_in[10];
    const float* Wr2 = (const float*)d_in[11], *br2 = (const float*)d_in[12];
    const float* att2= (const float*)d_in[13], *b2  = (const float*)d_in[14];
    const float* Wl3 = (const float*)d_in[15], *bl3 = (const float*)d_in[16];
    const float* Wr3 = (const float*)d_in[17], *br3 = (const float*)d_in[18];
    const float* att3= (const float*)d_in[19], *b3  = (const float*)d_in[20];

    int N = in_sizes[0] / 8;
    int E = in_sizes[1] / 2;
    int G = out_size / 64;
    int Etot = E + N;

    char* w = (char*)d_ws;
    auto carve = [&](size_t bytes) {
        void* p = (void*)w;
        w += (bytes + 255) & ~(size_t)255;
        return p;
    };
    int*      deg     = (int*)carve((size_t)N * 4);
    int*      row_off = (int*)carve((size_t)(N + 1) * 4);
    int*      cursor  = (int*)carve((size_t)N * 4);
    int*      csr_src = (int*)carve((size_t)Etot * 4);
    int*      pool_acc= (int*)carve((size_t)(2 * G * 32 + 64) * 4);  // gsum|gmax|done
    float*    gsum    = (float*)pool_acc;
    unsigned* gmax    = (unsigned*)(pool_acc + G * 32);
    int*      done    = pool_acc + 2 * G * 32;
    float*    bufA    = (float*)carve((size_t)N * 128 * 4);  // xl
    float*    bufB    = (float*)carve((size_t)N * 128 * 4);  // xr
    float*    bufC    = (float*)carve((size_t)N * 128 * 4);  // h (layer outputs)
    (void)ws_size; (void)n_in;

    // ---- init + CSR by dst (incl. self loops) ----
    k_init<<<128, 256, 0, stream>>>(deg, N, pool_acc, 2 * G * 32 + 1);
    k_hist<<<(Etot + 255) / 256, 256, 0, stream>>>(ei, E, N, deg);
    k_scan<<<1, 1024, 0, stream>>>(deg, N, row_off, cursor);
    k_scatter<<<(Etot + 255) / 256, 256, 0, stream>>>(ei, E, N, cursor, csr_src);

    int grdLin = (N + 31) / 32;
    int grdFused = (N + 3) / 4;

    // ---- Layer 1: K=8 -> 128 (H=2,C=64) ----
    k_linear2<8, 128><<<grdLin, 256, 0, stream>>>(x, N, Wl1, bl1, Wr1, br1, bufA, bufB);
    k_fused<128, 64><<<grdFused, 256, 0, stream>>>(row_off, csr_src, bufA, bufB, att1, b1, bufC, N);

    // ---- Layer 2: 128 -> 128 ----
    k_linear2<128, 128><<<grdLin, 256, 0, stream>>>(bufC, N, Wl2, bl2, Wr2, br2, bufA, bufB);
    k_fused<128, 64><<<grdFused, 256, 0, stream>>>(row_off, csr_src, bufA, bufB, att2, b2, bufC, N);

    // ---- Layer 3: 128 -> 32 (H=1,C=32) ----
    k_linear3<<<grdLin, 256, 0, stream>>>(bufC, N, Wl3, bl3, Wr3, br3, bufA, bufB);
    k_fused<32, 32><<<grdFused, 256, 0, stream>>>(row_off, csr_src, bufA, bufB, att3, b3, bufC, N);

    // ---- pooling (single kernel, last block finalizes) ----
    k_pool<<<256, 256, 0, stream>>>(bufC, batch, N, G, gsum, gmax, done, (float*)d_out);
}

// Round 9
// 520.103 us; speedup vs baseline: 1.2339x; 1.1211x over previous
//
#include <hip/hip_runtime.h>
#include <hip/hip_bf16.h>
#include <math.h>

// GATv2 3-layer GNN, MI355X. CSR-by-dst + fused online-softmax aggregation.
// R3/R4 proven config: register-tiled fp32 linear, 36-VGPR fused body,
//   2-kernel pooling, 64-thread lin3. (R6's bundled changes regressed; reverted.)
// R7/R8: xl stored bf16 for layers 1-2 -> halves the 8xXCD L2-fill floor
//     (fetch 200MB -> ~105MB per fused layer). All math fp32; layer 3 all-fp32.
//     (R8 = identical resubmit; R7 bench was an infra failure, kernel never ran.)

__device__ __forceinline__ float lrelu(float x) { return x > 0.f ? x : 0.2f * x; }
__device__ __forceinline__ float elu1(float x) { return x > 0.f ? x : expm1f(x); }

__device__ __forceinline__ unsigned f2ord(float x) {
    unsigned b = __float_as_uint(x);
    return (b & 0x80000000u) ? ~b : (b | 0x80000000u);
}
__device__ __forceinline__ float ord2f(unsigned u) {
    unsigned b = (u & 0x80000000u) ? (u & 0x7FFFFFFFu) : ~u;
    return __uint_as_float(b);
}
__device__ __forceinline__ unsigned short f2bf(float f) {   // RNE
    unsigned u = __float_as_uint(f);
    unsigned r = u + 0x7FFFu + ((u >> 16) & 1u);
    return (unsigned short)(r >> 16);
}

// ---------------- CSR build ----------------
__global__ void k_zero_i32(int* __restrict__ p, int n) {
    int i = blockIdx.x * blockDim.x + threadIdx.x;
    if (i < n) p[i] = 0;
}

__global__ void k_hist(const int* __restrict__ ei, int E, int N, int* __restrict__ deg) {
    int e = blockIdx.x * blockDim.x + threadIdx.x;
    int Etot = E + N;
    if (e >= Etot) return;
    int d = (e < E) ? ei[E + e] : (e - E);
    atomicAdd(&deg[d], 1);
}

__global__ void __launch_bounds__(1024) k_scan(const int* __restrict__ deg, int n,
                                               int* __restrict__ row_off, int* __restrict__ cursor) {
    __shared__ int wsum[16];
    __shared__ int sbase;
    int tid = threadIdx.x;
    int lane = tid & 63, w = tid >> 6;
    if (tid == 0) sbase = 0;
    __syncthreads();
    for (int start = 0; start < n; start += 1024) {
        int i = start + tid;
        int v = (i < n) ? deg[i] : 0;
        int s = v;
        #pragma unroll
        for (int d = 1; d < 64; d <<= 1) {
            int t = __shfl_up(s, d, 64);
            if (lane >= d) s += t;
        }
        if (lane == 63) wsum[w] = s;
        __syncthreads();
        int wbase = 0;
        for (int k = 0; k < w; k++) wbase += wsum[k];
        int excl = sbase + wbase + (s - v);
        if (i < n) { row_off[i] = excl; cursor[i] = excl; }
        __syncthreads();
        if (tid == 1023) sbase = excl + v;
        __syncthreads();
    }
    if (tid == 0) row_off[n] = sbase;
}

__global__ void k_scatter(const int* __restrict__ ei, int E, int N,
                          int* __restrict__ cursor,
                          int* __restrict__ csr_src) {
    int e = blockIdx.x * blockDim.x + threadIdx.x;
    int Etot = E + N;
    if (e >= Etot) return;
    int s, d;
    if (e < E) { s = ei[e]; d = ei[E + e]; } else { s = e - E; d = e - E; }
    int p = atomicAdd(&cursor[d], 1);
    csr_src[p] = s;
}

// ---------------- register-tiled dual linear, fp32 out (layer 3) ------------
template <int K, int MH>
__global__ void k_linear2(const float* __restrict__ x, int N,
                          const float* __restrict__ Wl, const float* __restrict__ bl,
                          const float* __restrict__ Wr, const float* __restrict__ br,
                          float* __restrict__ xl, float* __restrict__ xr) {
    constexpr int NCG = MH / 2;
    __shared__ float xs[32 * K];
    int tid = threadIdx.x;
    int node0 = blockIdx.x * 32;
    for (int idx = tid * 4; idx < 32 * K; idx += NCG * 4 * 4) {
        int node = node0 + idx / K;
        float4 v = make_float4(0.f, 0.f, 0.f, 0.f);
        if (node < N) v = *(const float4*)(x + (size_t)node0 * K + idx);
        *(float4*)(xs + idx) = v;
    }
    __syncthreads();

    int cg = tid % NCG;
    int ng = tid / NCG;
    bool rightSide = cg >= (MH / 4);
    int c = (rightSide ? cg - MH / 4 : cg) * 4;
    const float* W  = rightSide ? Wr : Wl;
    const float* bb = rightSide ? br : bl;
    float* out      = rightSide ? xr : xl;

    float acc[8][4];
    #pragma unroll
    for (int i = 0; i < 8; i++)
        #pragma unroll
        for (int j = 0; j < 4; j++) acc[i][j] = 0.f;

    const float* xrow = xs + ng * 8 * K;
    for (int k0 = 0; k0 < K; k0 += 4) {
        float4 wv[4];
        #pragma unroll
        for (int kk = 0; kk < 4; kk++)
            wv[kk] = *(const float4*)(W + (size_t)(k0 + kk) * MH + c);
        #pragma unroll
        for (int i = 0; i < 8; i++) {
            float4 xv = *(const float4*)(xrow + i * K + k0);
            float xvk[4] = {xv.x, xv.y, xv.z, xv.w};
            #pragma unroll
            for (int kk = 0; kk < 4; kk++) {
                acc[i][0] += xvk[kk] * wv[kk].x;
                acc[i][1] += xvk[kk] * wv[kk].y;
                acc[i][2] += xvk[kk] * wv[kk].z;
                acc[i][3] += xvk[kk] * wv[kk].w;
            }
        }
    }
    float4 bv = *(const float4*)(bb + c);
    #pragma unroll
    for (int i = 0; i < 8; i++) {
        int node = node0 + ng * 8 + i;
        if (node < N) {
            float4 o = make_float4(acc[i][0] + bv.x, acc[i][1] + bv.y,
                                   acc[i][2] + bv.z, acc[i][3] + bv.w);
            *(float4*)(out + (size_t)node * MH + c) = o;
        }
    }
}

// ---- variant for layers 1-2 (MH=128): xl written as bf16, xr fp32 -----------
template <int K>
__global__ void k_linear2b(const float* __restrict__ x, int N,
                           const float* __restrict__ Wl, const float* __restrict__ bl,
                           const float* __restrict__ Wr, const float* __restrict__ br,
                           unsigned short* __restrict__ xlb, float* __restrict__ xr) {
    constexpr int MH = 128, NCG = 64;
    __shared__ float xs[32 * K];
    int tid = threadIdx.x;
    int node0 = blockIdx.x * 32;
    for (int idx = tid * 4; idx < 32 * K; idx += NCG * 4 * 4) {
        int node = node0 + idx / K;
        float4 v = make_float4(0.f, 0.f, 0.f, 0.f);
        if (node < N) v = *(const float4*)(x + (size_t)node0 * K + idx);
        *(float4*)(xs + idx) = v;
    }
    __syncthreads();

    int cg = tid % NCG;
    int ng = tid / NCG;
    bool rightSide = cg >= (MH / 4);
    int c = (rightSide ? cg - MH / 4 : cg) * 4;
    const float* W  = rightSide ? Wr : Wl;
    const float* bb = rightSide ? br : bl;

    float acc[8][4];
    #pragma unroll
    for (int i = 0; i < 8; i++)
        #pragma unroll
        for (int j = 0; j < 4; j++) acc[i][j] = 0.f;

    const float* xrow = xs + ng * 8 * K;
    for (int k0 = 0; k0 < K; k0 += 4) {
        float4 wv[4];
        #pragma unroll
        for (int kk = 0; kk < 4; kk++)
            wv[kk] = *(const float4*)(W + (size_t)(k0 + kk) * MH + c);
        #pragma unroll
        for (int i = 0; i < 8; i++) {
            float4 xv = *(const float4*)(xrow + i * K + k0);
            float xvk[4] = {xv.x, xv.y, xv.z, xv.w};
            #pragma unroll
            for (int kk = 0; kk < 4; kk++) {
                acc[i][0] += xvk[kk] * wv[kk].x;
                acc[i][1] += xvk[kk] * wv[kk].y;
                acc[i][2] += xvk[kk] * wv[kk].z;
                acc[i][3] += xvk[kk] * wv[kk].w;
            }
        }
    }
    float4 bv = *(const float4*)(bb + c);
    #pragma unroll
    for (int i = 0; i < 8; i++) {
        int node = node0 + ng * 8 + i;
        if (node >= N) continue;
        float o0 = acc[i][0] + bv.x, o1 = acc[i][1] + bv.y;
        float o2 = acc[i][2] + bv.z, o3 = acc[i][3] + bv.w;
        if (rightSide) {
            *(float4*)(xr + (size_t)node * MH + c) = make_float4(o0, o1, o2, o3);
        } else {
            ushort4 ub = make_ushort4(f2bf(o0), f2bf(o1), f2bf(o2), f2bf(o3));
            *(ushort4*)(xlb + (size_t)node * MH + c) = ub;
        }
    }
}

// ---------------- fused attention+aggregate, bf16 xl (layers 1-2, HC=128) ----
__global__ void k_fusedb(const int* __restrict__ row_off, const int* __restrict__ csr_src,
                         const unsigned short* __restrict__ xlb, const float* __restrict__ xr,
                         const float* __restrict__ att, const float* __restrict__ bias,
                         float* __restrict__ hout, int N) {
    constexpr int HC = 128, CPL = 8, GROUP = 8;  // C=64: 8 lanes/head
    int wid = (blockIdx.x * blockDim.x + threadIdx.x) >> 6;
    int lane = threadIdx.x & 63;
    if (wid >= N) return;
    int slot = lane >> 4;
    int j = lane & 15;
    int c0 = j * CPL;

    int p0 = row_off[wid], p1 = row_off[wid + 1];

    float xrv[CPL], attv[CPL];
    {
        float4 a = *(const float4*)(xr + (size_t)wid * HC + c0);
        float4 b = *(const float4*)(xr + (size_t)wid * HC + c0 + 4);
        xrv[0] = a.x; xrv[1] = a.y; xrv[2] = a.z; xrv[3] = a.w;
        xrv[4] = b.x; xrv[5] = b.y; xrv[6] = b.z; xrv[7] = b.w;
        float4 c = *(const float4*)(att + c0);
        float4 d = *(const float4*)(att + c0 + 4);
        attv[0] = c.x; attv[1] = c.y; attv[2] = c.z; attv[3] = c.w;
        attv[4] = d.x; attv[5] = d.y; attv[6] = d.z; attv[7] = d.w;
    }

    float m = -INFINITY, den = 0.f;
    float acc[CPL];
    #pragma unroll
    for (int q = 0; q < CPL; q++) acc[q] = 0.f;

    int p = p0 + slot;
    int s = (p < p1) ? csr_src[p] : 0;
    while (p < p1) {
        int pn = p + 4;
        int sn = (pn < p1) ? csr_src[pn] : 0;
        int4 rv = *(const int4*)(xlb + (size_t)s * HC + c0);   // 8 bf16 in 16B
        float xlv[CPL];
        {
            unsigned u0 = (unsigned)rv.x, u1 = (unsigned)rv.y;
            unsigned u2 = (unsigned)rv.z, u3 = (unsigned)rv.w;
            xlv[0] = __uint_as_float(u0 << 16); xlv[1] = __uint_as_float(u0 & 0xFFFF0000u);
            xlv[2] = __uint_as_float(u1 << 16); xlv[3] = __uint_as_float(u1 & 0xFFFF0000u);
            xlv[4] = __uint_as_float(u2 << 16); xlv[5] = __uint_as_float(u2 & 0xFFFF0000u);
            xlv[6] = __uint_as_float(u3 << 16); xlv[7] = __uint_as_float(u3 & 0xFFFF0000u);
        }
        float part = 0.f;
        #pragma unroll
        for (int q = 0; q < CPL; q++) part += lrelu(xlv[q] + xrv[q]) * attv[q];
        #pragma unroll
        for (int msk = 1; msk < GROUP; msk <<= 1) part += __shfl_xor(part, msk, 64);
        float mnew = fmaxf(m, part);
        float corr = __expf(m - mnew);
        float ex = __expf(part - mnew);
        den = den * corr + ex;
        #pragma unroll
        for (int q = 0; q < CPL; q++) acc[q] = acc[q] * corr + ex * xlv[q];
        m = mnew;
        p = pn; s = sn;
    }
    float mAll = fmaxf(m, __shfl_xor(m, 16, 64));
    mAll = fmaxf(mAll, __shfl_xor(mAll, 32, 64));
    float scale = __expf(m - mAll);
    float dtot = den * scale;
    dtot += __shfl_xor(dtot, 16, 64);
    dtot += __shfl_xor(dtot, 32, 64);
    #pragma unroll
    for (int q = 0; q < CPL; q++) {
        float a = acc[q] * scale;
        a += __shfl_xor(a, 16, 64);
        a += __shfl_xor(a, 32, 64);
        acc[q] = a;
    }
    if (slot == 0) {
        float inv = 1.0f / (dtot + 1e-16f);
        #pragma unroll
        for (int q = 0; q < CPL; q++) {
            float v = acc[q] * inv + bias[c0 + q];
            hout[(size_t)wid * HC + c0 + q] = elu1(v);
        }
    }
}

// ---------------- fused attention+aggregate, fp32 (layer 3, HC=32) ----------
template <int CPL>
__device__ __forceinline__ void loadrow(const float* __restrict__ p, float* v) {
    if constexpr (CPL == 8) {
        float4 a = ((const float4*)p)[0];
        float4 b = ((const float4*)p)[1];
        v[0] = a.x; v[1] = a.y; v[2] = a.z; v[3] = a.w;
        v[4] = b.x; v[5] = b.y; v[6] = b.z; v[7] = b.w;
    } else {
        float2 a = ((const float2*)p)[0];
        v[0] = a.x; v[1] = a.y;
    }
}

template <int HC, int C>
__global__ void k_fused(const int* __restrict__ row_off, const int* __restrict__ csr_src,
                        const float* __restrict__ xl, const float* __restrict__ xr,
                        const float* __restrict__ att, const float* __restrict__ bias,
                        float* __restrict__ hout, int N) {
    constexpr int CPL = HC / 16;
    constexpr int GROUP = (16 * C) / HC;
    int wid = (blockIdx.x * blockDim.x + threadIdx.x) >> 6;
    int lane = threadIdx.x & 63;
    if (wid >= N) return;
    int slot = lane >> 4;
    int j = lane & 15;
    int c0 = j * CPL;

    int p0 = row_off[wid], p1 = row_off[wid + 1];

    float xrv[CPL], attv[CPL];
    loadrow<CPL>(xr + (size_t)wid * HC + c0, xrv);
    loadrow<CPL>(att + c0, attv);

    float m = -INFINITY, den = 0.f;
    float acc[CPL];
    #pragma unroll
    for (int q = 0; q < CPL; q++) acc[q] = 0.f;

    int p = p0 + slot;
    int s = (p < p1) ? csr_src[p] : 0;
    while (p < p1) {
        int pn = p + 4;
        int sn = (pn < p1) ? csr_src[pn] : 0;
        float xlv[CPL];
        loadrow<CPL>(xl + (size_t)s * HC + c0, xlv);
        float part = 0.f;
        #pragma unroll
        for (int q = 0; q < CPL; q++) part += lrelu(xlv[q] + xrv[q]) * attv[q];
        #pragma unroll
        for (int msk = 1; msk < GROUP; msk <<= 1) part += __shfl_xor(part, msk, 64);
        float mnew = fmaxf(m, part);
        float corr = __expf(m - mnew);
        float ex = __expf(part - mnew);
        den = den * corr + ex;
        #pragma unroll
        for (int q = 0; q < CPL; q++) acc[q] = acc[q] * corr + ex * xlv[q];
        m = mnew;
        p = pn; s = sn;
    }
    float mAll = fmaxf(m, __shfl_xor(m, 16, 64));
    mAll = fmaxf(mAll, __shfl_xor(mAll, 32, 64));
    float scale = __expf(m - mAll);
    float dtot = den * scale;
    dtot += __shfl_xor(dtot, 16, 64);
    dtot += __shfl_xor(dtot, 32, 64);
    #pragma unroll
    for (int q = 0; q < CPL; q++) {
        float a = acc[q] * scale;
        a += __shfl_xor(a, 16, 64);
        a += __shfl_xor(a, 32, 64);
        acc[q] = a;
    }
    if (slot == 0) {
        float inv = 1.0f / (dtot + 1e-16f);
        #pragma unroll
        for (int q = 0; q < CPL; q++) {
            float v = acc[q] * inv + bias[c0 + q];
            hout[(size_t)wid * HC + c0 + q] = elu1(v);
        }
    }
}

// ---------------- graph pooling (parallel, 2-stage) ----------------
__global__ void __launch_bounds__(256) k_pool_partial(
        const float* __restrict__ h, const int* __restrict__ batch, int N, int G,
        float* __restrict__ gsum, unsigned* __restrict__ gmax) {
    __shared__ float lsum[512];
    __shared__ unsigned lmax[512];
    int tid = threadIdx.x;
    for (int i = tid; i < G * 32; i += 256) { lsum[i] = 0.f; lmax[i] = 0u; }
    __syncthreads();
    int chunk = (N + gridDim.x - 1) / gridDim.x;
    int start = blockIdx.x * chunk;
    int end = min(N, start + chunk);
    int col = tid & 31, row = tid >> 5;
    int gc = -1; float ps = 0.f; unsigned pm = 0u;
    for (int i = start + row; i < end; i += 8) {
        int g = batch[i];
        if (g != gc) {
            if (gc >= 0) { atomicAdd(&lsum[gc * 32 + col], ps); atomicMax(&lmax[gc * 32 + col], pm); }
            gc = g; ps = 0.f; pm = 0u;
        }
        float v = h[(size_t)i * 32 + col];
        ps += v; pm = max(pm, f2ord(v));
    }
    if (gc >= 0) { atomicAdd(&lsum[gc * 32 + col], ps); atomicMax(&lmax[gc * 32 + col], pm); }
    __syncthreads();
    for (int i = tid; i < G * 32; i += 256) {
        if (lmax[i]) {
            atomicAdd(&gsum[i], lsum[i]);
            atomicMax(&gmax[i], lmax[i]);
        }
    }
}

__global__ void k_pool_final(const float* __restrict__ gsum, const unsigned* __restrict__ gmax,
                             const int* __restrict__ batch, int N, float* __restrict__ out) {
    int g = blockIdx.x;
    int t = threadIdx.x;
    __shared__ int s_cnt;
    if (t == 0) {
        int lo = 0, hi = N;
        while (lo < hi) { int m = (lo + hi) >> 1; if (batch[m] < g) lo = m + 1; else hi = m; }
        int a = lo;
        lo = a; hi = N;
        while (lo < hi) { int m = (lo + hi) >> 1; if (batch[m] < g + 1) lo = m + 1; else hi = m; }
        s_cnt = lo - a;
    }
    __syncthreads();
    if (t < 32) {
        out[g * 64 + t] = gsum[g * 32 + t] / (float)max(s_cnt, 1);
    } else {
        out[g * 64 + t] = ord2f(gmax[g * 32 + (t - 32)]);
    }
}

extern "C" void kernel_launch(void* const* d_in, const int* in_sizes, int n_in,
                              void* d_out, int out_size, void* d_ws, size_t ws_size,
                              hipStream_t stream) {
    const float* x      = (const float*)d_in[0];
    const int*   ei     = (const int*)d_in[1];
    const int*   batch  = (const int*)d_in[2];
    const float* Wl1 = (const float*)d_in[3],  *bl1 = (const float*)d_in[4];
    const float* Wr1 = (const float*)d_in[5],  *br1 = (const float*)d_in[6];
    const float* att1= (const float*)d_in[7],  *b1  = (const float*)d_in[8];
    const float* Wl2 = (const float*)d_in[9],  *bl2 = (const float*)d_in[10];
    const float* Wr2 = (const float*)d_in[11], *br2 = (const float*)d_in[12];
    const float* att2= (const float*)d_in[13], *b2  = (const float*)d_in[14];
    const float* Wl3 = (const float*)d_in[15], *bl3 = (const float*)d_in[16];
    const float* Wr3 = (const float*)d_in[17], *br3 = (const float*)d_in[18];
    const float* att3= (const float*)d_in[19], *b3  = (const float*)d_in[20];

    int N = in_sizes[0] / 8;
    int E = in_sizes[1] / 2;
    int G = out_size / 64;
    int Etot = E + N;

    char* w = (char*)d_ws;
    auto carve = [&](size_t bytes) {
        void* p = (void*)w;
        w += (bytes + 255) & ~(size_t)255;
        return p;
    };
    int*            deg     = (int*)carve((size_t)N * 4);
    int*            row_off = (int*)carve((size_t)(N + 1) * 4);
    int*            cursor  = (int*)carve((size_t)N * 4);
    int*            csr_src = (int*)carve((size_t)Etot * 4);
    float*          gsum    = (float*)carve((size_t)G * 32 * 4);
    unsigned*       gmax    = (unsigned*)carve((size_t)G * 32 * 4);
    unsigned short* xlb     = (unsigned short*)carve((size_t)N * 128 * 2);  // bf16 xl (layers 1-2)
    float*          bufA    = (float*)carve((size_t)N * 128 * 4);  // fp32 xl (layer 3)
    float*          bufB    = (float*)carve((size_t)N * 128 * 4);  // xr
    float*          bufC    = (float*)carve((size_t)N * 128 * 4);  // h (layer outputs)
    (void)ws_size; (void)n_in;

    // ---- CSR by dst (incl. self loops) + pool accumulator init ----
    k_zero_i32<<<(N + 255) / 256, 256, 0, stream>>>(deg, N);
    k_zero_i32<<<(2 * G * 32 + 255) / 256, 256, 0, stream>>>((int*)gsum, 2 * G * 32);
    k_hist<<<(Etot + 255) / 256, 256, 0, stream>>>(ei, E, N, deg);
    k_scan<<<1, 1024, 0, stream>>>(deg, N, row_off, cursor);
    k_scatter<<<(Etot + 255) / 256, 256, 0, stream>>>(ei, E, N, cursor, csr_src);

    int grdLin = (N + 31) / 32;
    int grdFused = (N + 3) / 4;

    // ---- Layer 1: K=8 -> 128 (H=2,C=64), bf16 xl ----
    k_linear2b<8><<<grdLin, 256, 0, stream>>>(x, N, Wl1, bl1, Wr1, br1, xlb, bufB);
    k_fusedb<<<grdFused, 256, 0, stream>>>(row_off, csr_src, xlb, bufB, att1, b1, bufC, N);

    // ---- Layer 2: 128 -> 128, bf16 xl ----
    k_linear2b<128><<<grdLin, 256, 0, stream>>>(bufC, N, Wl2, bl2, Wr2, br2, xlb, bufB);
    k_fusedb<<<grdFused, 256, 0, stream>>>(row_off, csr_src, xlb, bufB, att2, b2, bufC, N);

    // ---- Layer 3: 128 -> 32 (H=1,C=32), all fp32 ----
    k_linear2<128, 32><<<grdLin, 64, 0, stream>>>(bufC, N, Wl3, bl3, Wr3, br3, bufA, bufB);
    k_fused<32, 32><<<grdFused, 256, 0, stream>>>(row_off, csr_src, bufA, bufB, att3, b3, bufC, N);

    // ---- pooling ----
    k_pool_partial<<<256, 256, 0, stream>>>(bufC, batch, N, G, gsum, gmax);
    k_pool_final<<<G, 64, 0, stream>>>(gsum, gmax, batch, N, (float*)d_out);
}

// Round 10
// 514.631 us; speedup vs baseline: 1.2470x; 1.0106x over previous
//
#include <hip/hip_runtime.h>
#include <hip/hip_bf16.h>
#include <math.h>

// GATv2 3-layer GNN, MI355X. CSR-by-dst + fused online-softmax aggregation.
// R9: bf16 xl (layers 1-2): fetch 200->98MB, absmax 4.9e-4. Now VALU-bound (77%).
// R10: defer-max (THR=8) in both fused kernels -> 1 exp/edge common path;
//      lin3 256-thread blocks (was 1-wave/block occupancy-capped).

__device__ __forceinline__ float lrelu(float x) { return x > 0.f ? x : 0.2f * x; }
__device__ __forceinline__ float elu1(float x) { return x > 0.f ? x : expm1f(x); }

__device__ __forceinline__ unsigned f2ord(float x) {
    unsigned b = __float_as_uint(x);
    return (b & 0x80000000u) ? ~b : (b | 0x80000000u);
}
__device__ __forceinline__ float ord2f(unsigned u) {
    unsigned b = (u & 0x80000000u) ? (u & 0x7FFFFFFFu) : ~u;
    return __uint_as_float(b);
}
__device__ __forceinline__ unsigned short f2bf(float f) {   // RNE
    unsigned u = __float_as_uint(f);
    unsigned r = u + 0x7FFFu + ((u >> 16) & 1u);
    return (unsigned short)(r >> 16);
}

// ---------------- CSR build ----------------
__global__ void k_zero_i32(int* __restrict__ p, int n) {
    int i = blockIdx.x * blockDim.x + threadIdx.x;
    if (i < n) p[i] = 0;
}

__global__ void k_hist(const int* __restrict__ ei, int E, int N, int* __restrict__ deg) {
    int e = blockIdx.x * blockDim.x + threadIdx.x;
    int Etot = E + N;
    if (e >= Etot) return;
    int d = (e < E) ? ei[E + e] : (e - E);
    atomicAdd(&deg[d], 1);
}

__global__ void __launch_bounds__(1024) k_scan(const int* __restrict__ deg, int n,
                                               int* __restrict__ row_off, int* __restrict__ cursor) {
    __shared__ int wsum[16];
    __shared__ int sbase;
    int tid = threadIdx.x;
    int lane = tid & 63, w = tid >> 6;
    if (tid == 0) sbase = 0;
    __syncthreads();
    for (int start = 0; start < n; start += 1024) {
        int i = start + tid;
        int v = (i < n) ? deg[i] : 0;
        int s = v;
        #pragma unroll
        for (int d = 1; d < 64; d <<= 1) {
            int t = __shfl_up(s, d, 64);
            if (lane >= d) s += t;
        }
        if (lane == 63) wsum[w] = s;
        __syncthreads();
        int wbase = 0;
        for (int k = 0; k < w; k++) wbase += wsum[k];
        int excl = sbase + wbase + (s - v);
        if (i < n) { row_off[i] = excl; cursor[i] = excl; }
        __syncthreads();
        if (tid == 1023) sbase = excl + v;
        __syncthreads();
    }
    if (tid == 0) row_off[n] = sbase;
}

__global__ void k_scatter(const int* __restrict__ ei, int E, int N,
                          int* __restrict__ cursor,
                          int* __restrict__ csr_src) {
    int e = blockIdx.x * blockDim.x + threadIdx.x;
    int Etot = E + N;
    if (e >= Etot) return;
    int s, d;
    if (e < E) { s = ei[e]; d = ei[E + e]; } else { s = e - E; d = e - E; }
    int p = atomicAdd(&cursor[d], 1);
    csr_src[p] = s;
}

// ---- dual linear variant (layers 1-2, MH=128): xl written bf16, xr fp32 -----
template <int K>
__global__ void k_linear2b(const float* __restrict__ x, int N,
                           const float* __restrict__ Wl, const float* __restrict__ bl,
                           const float* __restrict__ Wr, const float* __restrict__ br,
                           unsigned short* __restrict__ xlb, float* __restrict__ xr) {
    constexpr int MH = 128, NCG = 64;
    __shared__ float xs[32 * K];
    int tid = threadIdx.x;
    int node0 = blockIdx.x * 32;
    for (int idx = tid * 4; idx < 32 * K; idx += NCG * 4 * 4) {
        int node = node0 + idx / K;
        float4 v = make_float4(0.f, 0.f, 0.f, 0.f);
        if (node < N) v = *(const float4*)(x + (size_t)node0 * K + idx);
        *(float4*)(xs + idx) = v;
    }
    __syncthreads();

    int cg = tid % NCG;
    int ng = tid / NCG;
    bool rightSide = cg >= (MH / 4);
    int c = (rightSide ? cg - MH / 4 : cg) * 4;
    const float* W  = rightSide ? Wr : Wl;
    const float* bb = rightSide ? br : bl;

    float acc[8][4];
    #pragma unroll
    for (int i = 0; i < 8; i++)
        #pragma unroll
        for (int j = 0; j < 4; j++) acc[i][j] = 0.f;

    const float* xrow = xs + ng * 8 * K;
    for (int k0 = 0; k0 < K; k0 += 4) {
        float4 wv[4];
        #pragma unroll
        for (int kk = 0; kk < 4; kk++)
            wv[kk] = *(const float4*)(W + (size_t)(k0 + kk) * MH + c);
        #pragma unroll
        for (int i = 0; i < 8; i++) {
            float4 xv = *(const float4*)(xrow + i * K + k0);
            float xvk[4] = {xv.x, xv.y, xv.z, xv.w};
            #pragma unroll
            for (int kk = 0; kk < 4; kk++) {
                acc[i][0] += xvk[kk] * wv[kk].x;
                acc[i][1] += xvk[kk] * wv[kk].y;
                acc[i][2] += xvk[kk] * wv[kk].z;
                acc[i][3] += xvk[kk] * wv[kk].w;
            }
        }
    }
    float4 bv = *(const float4*)(bb + c);
    #pragma unroll
    for (int i = 0; i < 8; i++) {
        int node = node0 + ng * 8 + i;
        if (node >= N) continue;
        float o0 = acc[i][0] + bv.x, o1 = acc[i][1] + bv.y;
        float o2 = acc[i][2] + bv.z, o3 = acc[i][3] + bv.w;
        if (rightSide) {
            *(float4*)(xr + (size_t)node * MH + c) = make_float4(o0, o1, o2, o3);
        } else {
            ushort4 ub = make_ushort4(f2bf(o0), f2bf(o1), f2bf(o2), f2bf(o3));
            *(ushort4*)(xlb + (size_t)node * MH + c) = ub;
        }
    }
}

// ---------------- layer-3 linear (128->32), 256-thread blocks ----------------
__global__ void __launch_bounds__(256) k_linear3(
        const float* __restrict__ x, int N,
        const float* __restrict__ Wl, const float* __restrict__ bl,
        const float* __restrict__ Wr, const float* __restrict__ br,
        float* __restrict__ xl, float* __restrict__ xr) {
    __shared__ float xs[32 * 128];
    int tid = threadIdx.x;
    int node0 = blockIdx.x * 32;
    for (int idx = tid * 4; idx < 32 * 128; idx += 256 * 4) {
        int node = node0 + idx / 128;
        float4 v = make_float4(0.f, 0.f, 0.f, 0.f);
        if (node < N) v = *(const float4*)(x + (size_t)node0 * 128 + idx);
        *(float4*)(xs + idx) = v;
    }
    __syncthreads();
    int cg = tid & 15, ng = tid >> 4;   // 16 col-groups x 16 node-groups(2 nodes)
    bool rightSide = cg >= 8;
    int c = (rightSide ? cg - 8 : cg) * 4;
    const float* W  = rightSide ? Wr : Wl;
    const float* bb = rightSide ? br : bl;
    float* out      = rightSide ? xr : xl;

    float acc[2][4];
    #pragma unroll
    for (int i = 0; i < 2; i++)
        #pragma unroll
        for (int j = 0; j < 4; j++) acc[i][j] = 0.f;

    const float* xrow = xs + ng * 2 * 128;
    for (int k0 = 0; k0 < 128; k0 += 4) {
        float4 wv[4];
        #pragma unroll
        for (int kk = 0; kk < 4; kk++)
            wv[kk] = *(const float4*)(W + (size_t)(k0 + kk) * 32 + c);
        #pragma unroll
        for (int i = 0; i < 2; i++) {
            float4 xv = *(const float4*)(xrow + i * 128 + k0);
            float xvk[4] = {xv.x, xv.y, xv.z, xv.w};
            #pragma unroll
            for (int kk = 0; kk < 4; kk++) {
                acc[i][0] += xvk[kk] * wv[kk].x;
                acc[i][1] += xvk[kk] * wv[kk].y;
                acc[i][2] += xvk[kk] * wv[kk].z;
                acc[i][3] += xvk[kk] * wv[kk].w;
            }
        }
    }
    float4 bv = *(const float4*)(bb + c);
    #pragma unroll
    for (int i = 0; i < 2; i++) {
        int node = node0 + ng * 2 + i;
        if (node < N) {
            float4 o = make_float4(acc[i][0] + bv.x, acc[i][1] + bv.y,
                                   acc[i][2] + bv.z, acc[i][3] + bv.w);
            *(float4*)(out + (size_t)node * 32 + c) = o;
        }
    }
}

// ---------------- fused attention+aggregate, bf16 xl (layers 1-2, HC=128) ----
// Defer-max online softmax: keep reference max m; rescale only when a score
// exceeds m+8. Common path: 1 exp + 8 fma per edge (no per-col rescale).
__global__ void k_fusedb(const int* __restrict__ row_off, const int* __restrict__ csr_src,
                         const unsigned short* __restrict__ xlb, const float* __restrict__ xr,
                         const float* __restrict__ att, const float* __restrict__ bias,
                         float* __restrict__ hout, int N) {
    constexpr int HC = 128, CPL = 8, GROUP = 8;  // C=64: 8 lanes/head
    int wid = (blockIdx.x * blockDim.x + threadIdx.x) >> 6;
    int lane = threadIdx.x & 63;
    if (wid >= N) return;
    int slot = lane >> 4;
    int j = lane & 15;
    int c0 = j * CPL;

    int p0 = row_off[wid], p1 = row_off[wid + 1];

    float xrv[CPL], attv[CPL];
    {
        float4 a = *(const float4*)(xr + (size_t)wid * HC + c0);
        float4 b = *(const float4*)(xr + (size_t)wid * HC + c0 + 4);
        xrv[0] = a.x; xrv[1] = a.y; xrv[2] = a.z; xrv[3] = a.w;
        xrv[4] = b.x; xrv[5] = b.y; xrv[6] = b.z; xrv[7] = b.w;
        float4 c = *(const float4*)(att + c0);
        float4 d = *(const float4*)(att + c0 + 4);
        attv[0] = c.x; attv[1] = c.y; attv[2] = c.z; attv[3] = c.w;
        attv[4] = d.x; attv[5] = d.y; attv[6] = d.z; attv[7] = d.w;
    }

    float m = -INFINITY, den = 0.f;
    float acc[CPL];
    #pragma unroll
    for (int q = 0; q < CPL; q++) acc[q] = 0.f;

    int p = p0 + slot;
    int s = (p < p1) ? csr_src[p] : 0;
    while (p < p1) {
        int pn = p + 4;
        int sn = (pn < p1) ? csr_src[pn] : 0;
        int4 rv = *(const int4*)(xlb + (size_t)s * HC + c0);   // 8 bf16 in 16B
        float xlv[CPL];
        {
            unsigned u0 = (unsigned)rv.x, u1 = (unsigned)rv.y;
            unsigned u2 = (unsigned)rv.z, u3 = (unsigned)rv.w;
            xlv[0] = __uint_as_float(u0 << 16); xlv[1] = __uint_as_float(u0 & 0xFFFF0000u);
            xlv[2] = __uint_as_float(u1 << 16); xlv[3] = __uint_as_float(u1 & 0xFFFF0000u);
            xlv[4] = __uint_as_float(u2 << 16); xlv[5] = __uint_as_float(u2 & 0xFFFF0000u);
            xlv[6] = __uint_as_float(u3 << 16); xlv[7] = __uint_as_float(u3 & 0xFFFF0000u);
        }
        float part = 0.f;
        #pragma unroll
        for (int q = 0; q < CPL; q++) {
            float t = xlv[q] + xrv[q];
            part = fmaf(fmaxf(t, 0.2f * t), attv[q], part);
        }
        #pragma unroll
        for (int msk = 1; msk < GROUP; msk <<= 1) part += __shfl_xor(part, msk, 64);
        // defer-max: rescale only on big new max (exp(part-m) <= e^8 bounded)
        if (part > m + 8.f) {
            float corr = __expf(m - part);   // m=-inf -> 0 (zeroes empty state)
            den *= corr;
            #pragma unroll
            for (int q = 0; q < CPL; q++) acc[q] *= corr;
            m = part;
        }
        float ex = __expf(part - m);
        den += ex;
        #pragma unroll
        for (int q = 0; q < CPL; q++) acc[q] = fmaf(ex, xlv[q], acc[q]);
        p = pn; s = sn;
    }
    float mAll = fmaxf(m, __shfl_xor(m, 16, 64));
    mAll = fmaxf(mAll, __shfl_xor(mAll, 32, 64));
    float scale = __expf(m - mAll);
    float dtot = den * scale;
    dtot += __shfl_xor(dtot, 16, 64);
    dtot += __shfl_xor(dtot, 32, 64);
    #pragma unroll
    for (int q = 0; q < CPL; q++) {
        float a = acc[q] * scale;
        a += __shfl_xor(a, 16, 64);
        a += __shfl_xor(a, 32, 64);
        acc[q] = a;
    }
    if (slot == 0) {
        float inv = 1.0f / (dtot + 1e-16f);
        #pragma unroll
        for (int q = 0; q < CPL; q++) {
            float v = acc[q] * inv + bias[c0 + q];
            hout[(size_t)wid * HC + c0 + q] = elu1(v);
        }
    }
}

// ---------------- fused attention+aggregate, fp32 (layer 3, HC=32) ----------
template <int CPL>
__device__ __forceinline__ void loadrow(const float* __restrict__ p, float* v) {
    if constexpr (CPL == 8) {
        float4 a = ((const float4*)p)[0];
        float4 b = ((const float4*)p)[1];
        v[0] = a.x; v[1] = a.y; v[2] = a.z; v[3] = a.w;
        v[4] = b.x; v[5] = b.y; v[6] = b.z; v[7] = b.w;
    } else {
        float2 a = ((const float2*)p)[0];
        v[0] = a.x; v[1] = a.y;
    }
}

template <int HC, int C>
__global__ void k_fused(const int* __restrict__ row_off, const int* __restrict__ csr_src,
                        const float* __restrict__ xl, const float* __restrict__ xr,
                        const float* __restrict__ att, const float* __restrict__ bias,
                        float* __restrict__ hout, int N) {
    constexpr int CPL = HC / 16;
    constexpr int GROUP = (16 * C) / HC;
    int wid = (blockIdx.x * blockDim.x + threadIdx.x) >> 6;
    int lane = threadIdx.x & 63;
    if (wid >= N) return;
    int slot = lane >> 4;
    int j = lane & 15;
    int c0 = j * CPL;

    int p0 = row_off[wid], p1 = row_off[wid + 1];

    float xrv[CPL], attv[CPL];
    loadrow<CPL>(xr + (size_t)wid * HC + c0, xrv);
    loadrow<CPL>(att + c0, attv);

    float m = -INFINITY, den = 0.f;
    float acc[CPL];
    #pragma unroll
    for (int q = 0; q < CPL; q++) acc[q] = 0.f;

    int p = p0 + slot;
    int s = (p < p1) ? csr_src[p] : 0;
    while (p < p1) {
        int pn = p + 4;
        int sn = (pn < p1) ? csr_src[pn] : 0;
        float xlv[CPL];
        loadrow<CPL>(xl + (size_t)s * HC + c0, xlv);
        float part = 0.f;
        #pragma unroll
        for (int q = 0; q < CPL; q++) {
            float t = xlv[q] + xrv[q];
            part = fmaf(fmaxf(t, 0.2f * t), attv[q], part);
        }
        #pragma unroll
        for (int msk = 1; msk < GROUP; msk <<= 1) part += __shfl_xor(part, msk, 64);
        if (part > m + 8.f) {
            float corr = __expf(m - part);
            den *= corr;
            #pragma unroll
            for (int q = 0; q < CPL; q++) acc[q] *= corr;
            m = part;
        }
        float ex = __expf(part - m);
        den += ex;
        #pragma unroll
        for (int q = 0; q < CPL; q++) acc[q] = fmaf(ex, xlv[q], acc[q]);
        p = pn; s = sn;
    }
    float mAll = fmaxf(m, __shfl_xor(m, 16, 64));
    mAll = fmaxf(mAll, __shfl_xor(mAll, 32, 64));
    float scale = __expf(m - mAll);
    float dtot = den * scale;
    dtot += __shfl_xor(dtot, 16, 64);
    dtot += __shfl_xor(dtot, 32, 64);
    #pragma unroll
    for (int q = 0; q < CPL; q++) {
        float a = acc[q] * scale;
        a += __shfl_xor(a, 16, 64);
        a += __shfl_xor(a, 32, 64);
        acc[q] = a;
    }
    if (slot == 0) {
        float inv = 1.0f / (dtot + 1e-16f);
        #pragma unroll
        for (int q = 0; q < CPL; q++) {
            float v = acc[q] * inv + bias[c0 + q];
            hout[(size_t)wid * HC + c0 + q] = elu1(v);
        }
    }
}

// ---------------- graph pooling (parallel, 2-stage) ----------------
__global__ void __launch_bounds__(256) k_pool_partial(
        const float* __restrict__ h, const int* __restrict__ batch, int N, int G,
        float* __restrict__ gsum, unsigned* __restrict__ gmax) {
    __shared__ float lsum[512];
    __shared__ unsigned lmax[512];
    int tid = threadIdx.x;
    for (int i = tid; i < G * 32; i += 256) { lsum[i] = 0.f; lmax[i] = 0u; }
    __syncthreads();
    int chunk = (N + gridDim.x - 1) / gridDim.x;
    int start = blockIdx.x * chunk;
    int end = min(N, start + chunk);
    int col = tid & 31, row = tid >> 5;
    int gc = -1; float ps = 0.f; unsigned pm = 0u;
    for (int i = start + row; i < end; i += 8) {
        int g = batch[i];
        if (g != gc) {
            if (gc >= 0) { atomicAdd(&lsum[gc * 32 + col], ps); atomicMax(&lmax[gc * 32 + col], pm); }
            gc = g; ps = 0.f; pm = 0u;
        }
        float v = h[(size_t)i * 32 + col];
        ps += v; pm = max(pm, f2ord(v));
    }
    if (gc >= 0) { atomicAdd(&lsum[gc * 32 + col], ps); atomicMax(&lmax[gc * 32 + col], pm); }
    __syncthreads();
    for (int i = tid; i < G * 32; i += 256) {
        if (lmax[i]) {
            atomicAdd(&gsum[i], lsum[i]);
            atomicMax(&gmax[i], lmax[i]);
        }
    }
}

__global__ void k_pool_final(const float* __restrict__ gsum, const unsigned* __restrict__ gmax,
                             const int* __restrict__ batch, int N, float* __restrict__ out) {
    int g = blockIdx.x;
    int t = threadIdx.x;
    __shared__ int s_cnt;
    if (t == 0) {
        int lo = 0, hi = N;
        while (lo < hi) { int m = (lo + hi) >> 1; if (batch[m] < g) lo = m + 1; else hi = m; }
        int a = lo;
        lo = a; hi = N;
        while (lo < hi) { int m = (lo + hi) >> 1; if (batch[m] < g + 1) lo = m + 1; else hi = m; }
        s_cnt = lo - a;
    }
    __syncthreads();
    if (t < 32) {
        out[g * 64 + t] = gsum[g * 32 + t] / (float)max(s_cnt, 1);
    } else {
        out[g * 64 + t] = ord2f(gmax[g * 32 + (t - 32)]);
    }
}

extern "C" void kernel_launch(void* const* d_in, const int* in_sizes, int n_in,
                              void* d_out, int out_size, void* d_ws, size_t ws_size,
                              hipStream_t stream) {
    const float* x      = (const float*)d_in[0];
    const int*   ei     = (const int*)d_in[1];
    const int*   batch  = (const int*)d_in[2];
    const float* Wl1 = (const float*)d_in[3],  *bl1 = (const float*)d_in[4];
    const float* Wr1 = (const float*)d_in[5],  *br1 = (const float*)d_in[6];
    const float* att1= (const float*)d_in[7],  *b1  = (const float*)d_in[8];
    const float* Wl2 = (const float*)d_in[9],  *bl2 = (const float*)d_in[10];
    const float* Wr2 = (const float*)d_in[11], *br2 = (const float*)d_in[12];
    const float* att2= (const float*)d_in[13], *b2  = (const float*)d_in[14];
    const float* Wl3 = (const float*)d_in[15], *bl3 = (const float*)d_in[16];
    const float* Wr3 = (const float*)d_in[17], *br3 = (const float*)d_in[18];
    const float* att3= (const float*)d_in[19], *b3  = (const float*)d_in[20];

    int N = in_sizes[0] / 8;
    int E = in_sizes[1] / 2;
    int G = out_size / 64;
    int Etot = E + N;

    char* w = (char*)d_ws;
    auto carve = [&](size_t bytes) {
        void* p = (void*)w;
        w += (bytes + 255) & ~(size_t)255;
        return p;
    };
    int*            deg     = (int*)carve((size_t)N * 4);
    int*            row_off = (int*)carve((size_t)(N + 1) * 4);
    int*            cursor  = (int*)carve((size_t)N * 4);
    int*            csr_src = (int*)carve((size_t)Etot * 4);
    float*          gsum    = (float*)carve((size_t)G * 32 * 4);
    unsigned*       gmax    = (unsigned*)carve((size_t)G * 32 * 4);
    unsigned short* xlb     = (unsigned short*)carve((size_t)N * 128 * 2);  // bf16 xl (layers 1-2)
    float*          bufA    = (float*)carve((size_t)N * 128 * 4);  // fp32 xl (layer 3)
    float*          bufB    = (float*)carve((size_t)N * 128 * 4);  // xr
    float*          bufC    = (float*)carve((size_t)N * 128 * 4);  // h (layer outputs)
    (void)ws_size; (void)n_in;

    // ---- CSR by dst (incl. self loops) + pool accumulator init ----
    k_zero_i32<<<(N + 255) / 256, 256, 0, stream>>>(deg, N);
    k_zero_i32<<<(2 * G * 32 + 255) / 256, 256, 0, stream>>>((int*)gsum, 2 * G * 32);
    k_hist<<<(Etot + 255) / 256, 256, 0, stream>>>(ei, E, N, deg);
    k_scan<<<1, 1024, 0, stream>>>(deg, N, row_off, cursor);
    k_scatter<<<(Etot + 255) / 256, 256, 0, stream>>>(ei, E, N, cursor, csr_src);

    int grdLin = (N + 31) / 32;
    int grdFused = (N + 3) / 4;

    // ---- Layer 1: K=8 -> 128 (H=2,C=64), bf16 xl ----
    k_linear2b<8><<<grdLin, 256, 0, stream>>>(x, N, Wl1, bl1, Wr1, br1, xlb, bufB);
    k_fusedb<<<grdFused, 256, 0, stream>>>(row_off, csr_src, xlb, bufB, att1, b1, bufC, N);

    // ---- Layer 2: 128 -> 128, bf16 xl ----
    k_linear2b<128><<<grdLin, 256, 0, stream>>>(bufC, N, Wl2, bl2, Wr2, br2, xlb, bufB);
    k_fusedb<<<grdFused, 256, 0, stream>>>(row_off, csr_src, xlb, bufB, att2, b2, bufC, N);

    // ---- Layer 3: 128 -> 32 (H=1,C=32), all fp32 ----
    k_linear3<<<grdLin, 256, 0, stream>>>(bufC, N, Wl3, bl3, Wr3, br3, bufA, bufB);
    k_fused<32, 32><<<grdFused, 256, 0, stream>>>(row_off, csr_src, bufA, bufB, att3, b3, bufC, N);

    // ---- pooling ----
    k_pool_partial<<<256, 256, 0, stream>>>(bufC, batch, N, G, gsum, gmax);
    k_pool_final<<<G, 64, 0, stream>>>(gsum, gmax, batch, N, (float*)d_out);
}

// Round 11
// 481.326 us; speedup vs baseline: 1.3333x; 1.0692x over previous
//
#include <hip/hip_runtime.h>
#include <hip/hip_bf16.h>
#include <math.h>

// GATv2 3-layer GNN, MI355X. CSR-by-dst + fused online-softmax aggregation.
// R9: bf16 xl (layers 1-2). R10: defer-max. Now outstanding-miss-limited.
// R11: parallel 3-kernel scan (was single-block serial); k_fusedb 2-deep
//      pipelined gathers (8 outstanding/wave, was 4).

__device__ __forceinline__ float lrelu(float x) { return x > 0.f ? x : 0.2f * x; }
__device__ __forceinline__ float elu1(float x) { return x > 0.f ? x : expm1f(x); }

__device__ __forceinline__ unsigned f2ord(float x) {
    unsigned b = __float_as_uint(x);
    return (b & 0x80000000u) ? ~b : (b | 0x80000000u);
}
__device__ __forceinline__ float ord2f(unsigned u) {
    unsigned b = (u & 0x80000000u) ? (u & 0x7FFFFFFFu) : ~u;
    return __uint_as_float(b);
}
__device__ __forceinline__ unsigned short f2bf(float f) {   // RNE
    unsigned u = __float_as_uint(f);
    unsigned r = u + 0x7FFFu + ((u >> 16) & 1u);
    return (unsigned short)(r >> 16);
}

// ---------------- CSR build ----------------
__global__ void k_zero_i32(int* __restrict__ p, int n) {
    int i = blockIdx.x * blockDim.x + threadIdx.x;
    if (i < n) p[i] = 0;
}

__global__ void k_hist(const int* __restrict__ ei, int E, int N, int* __restrict__ deg) {
    int e = blockIdx.x * blockDim.x + threadIdx.x;
    int Etot = E + N;
    if (e >= Etot) return;
    int d = (e < E) ? ei[E + e] : (e - E);
    atomicAdd(&deg[d], 1);
}

// parallel scan stage 1: per-block (1024 elems) exclusive prefix + block total
__global__ void __launch_bounds__(1024) k_scan_blk(
        const int* __restrict__ deg, int n,
        int* __restrict__ part, int* __restrict__ bsum) {
    __shared__ int wsum[16];
    int tid = threadIdx.x;
    int lane = tid & 63, w = tid >> 6;
    int i = blockIdx.x * 1024 + tid;
    int v = (i < n) ? deg[i] : 0;
    int s = v;
    #pragma unroll
    for (int d = 1; d < 64; d <<= 1) {
        int t = __shfl_up(s, d, 64);
        if (lane >= d) s += t;
    }
    if (lane == 63) wsum[w] = s;
    __syncthreads();
    int wbase = 0;
    for (int k = 0; k < w; k++) wbase += wsum[k];
    if (i < n) part[i] = wbase + (s - v);
    if (tid == 1023) bsum[blockIdx.x] = wbase + s;
}

// stage 2: single wave scans block totals (nb <= a few thousand via chunks)
__global__ void k_scan_top(const int* __restrict__ bsum, int nb,
                           int* __restrict__ boff, int* __restrict__ row_off, int n) {
    int lane = threadIdx.x;   // 64 threads
    int base = 0;
    for (int st = 0; st < nb; st += 64) {
        int i = st + lane;
        int v = (i < nb) ? bsum[i] : 0;
        int s = v;
        #pragma unroll
        for (int d = 1; d < 64; d <<= 1) {
            int t = __shfl_up(s, d, 64);
            if (lane >= d) s += t;
        }
        if (i < nb) boff[i] = base + (s - v);
        base += __shfl(s, 63, 64);
    }
    if (lane == 0) row_off[n] = base;
}

// stage 3: row_off/cursor = part + block offset
__global__ void __launch_bounds__(1024) k_scan_add(
        const int* __restrict__ part, const int* __restrict__ boff, int n,
        int* __restrict__ row_off, int* __restrict__ cursor) {
    int i = blockIdx.x * 1024 + threadIdx.x;
    if (i < n) {
        int r = part[i] + boff[blockIdx.x];
        row_off[i] = r;
        cursor[i] = r;
    }
}

__global__ void k_scatter(const int* __restrict__ ei, int E, int N,
                          int* __restrict__ cursor,
                          int* __restrict__ csr_src) {
    int e = blockIdx.x * blockDim.x + threadIdx.x;
    int Etot = E + N;
    if (e >= Etot) return;
    int s, d;
    if (e < E) { s = ei[e]; d = ei[E + e]; } else { s = e - E; d = e - E; }
    int p = atomicAdd(&cursor[d], 1);
    csr_src[p] = s;
}

// ---- dual linear variant (layers 1-2, MH=128): xl written bf16, xr fp32 -----
template <int K>
__global__ void k_linear2b(const float* __restrict__ x, int N,
                           const float* __restrict__ Wl, const float* __restrict__ bl,
                           const float* __restrict__ Wr, const float* __restrict__ br,
                           unsigned short* __restrict__ xlb, float* __restrict__ xr) {
    constexpr int MH = 128, NCG = 64;
    __shared__ float xs[32 * K];
    int tid = threadIdx.x;
    int node0 = blockIdx.x * 32;
    for (int idx = tid * 4; idx < 32 * K; idx += NCG * 4 * 4) {
        int node = node0 + idx / K;
        float4 v = make_float4(0.f, 0.f, 0.f, 0.f);
        if (node < N) v = *(const float4*)(x + (size_t)node0 * K + idx);
        *(float4*)(xs + idx) = v;
    }
    __syncthreads();

    int cg = tid % NCG;
    int ng = tid / NCG;
    bool rightSide = cg >= (MH / 4);
    int c = (rightSide ? cg - MH / 4 : cg) * 4;
    const float* W  = rightSide ? Wr : Wl;
    const float* bb = rightSide ? br : bl;

    float acc[8][4];
    #pragma unroll
    for (int i = 0; i < 8; i++)
        #pragma unroll
        for (int j = 0; j < 4; j++) acc[i][j] = 0.f;

    const float* xrow = xs + ng * 8 * K;
    for (int k0 = 0; k0 < K; k0 += 4) {
        float4 wv[4];
        #pragma unroll
        for (int kk = 0; kk < 4; kk++)
            wv[kk] = *(const float4*)(W + (size_t)(k0 + kk) * MH + c);
        #pragma unroll
        for (int i = 0; i < 8; i++) {
            float4 xv = *(const float4*)(xrow + i * K + k0);
            float xvk[4] = {xv.x, xv.y, xv.z, xv.w};
            #pragma unroll
            for (int kk = 0; kk < 4; kk++) {
                acc[i][0] += xvk[kk] * wv[kk].x;
                acc[i][1] += xvk[kk] * wv[kk].y;
                acc[i][2] += xvk[kk] * wv[kk].z;
                acc[i][3] += xvk[kk] * wv[kk].w;
            }
        }
    }
    float4 bv = *(const float4*)(bb + c);
    #pragma unroll
    for (int i = 0; i < 8; i++) {
        int node = node0 + ng * 8 + i;
        if (node >= N) continue;
        float o0 = acc[i][0] + bv.x, o1 = acc[i][1] + bv.y;
        float o2 = acc[i][2] + bv.z, o3 = acc[i][3] + bv.w;
        if (rightSide) {
            *(float4*)(xr + (size_t)node * MH + c) = make_float4(o0, o1, o2, o3);
        } else {
            ushort4 ub = make_ushort4(f2bf(o0), f2bf(o1), f2bf(o2), f2bf(o3));
            *(ushort4*)(xlb + (size_t)node * MH + c) = ub;
        }
    }
}

// ---------------- layer-3 linear (128->32), 256-thread blocks ----------------
__global__ void __launch_bounds__(256) k_linear3(
        const float* __restrict__ x, int N,
        const float* __restrict__ Wl, const float* __restrict__ bl,
        const float* __restrict__ Wr, const float* __restrict__ br,
        float* __restrict__ xl, float* __restrict__ xr) {
    __shared__ float xs[32 * 128];
    int tid = threadIdx.x;
    int node0 = blockIdx.x * 32;
    for (int idx = tid * 4; idx < 32 * 128; idx += 256 * 4) {
        int node = node0 + idx / 128;
        float4 v = make_float4(0.f, 0.f, 0.f, 0.f);
        if (node < N) v = *(const float4*)(x + (size_t)node0 * 128 + idx);
        *(float4*)(xs + idx) = v;
    }
    __syncthreads();
    int cg = tid & 15, ng = tid >> 4;
    bool rightSide = cg >= 8;
    int c = (rightSide ? cg - 8 : cg) * 4;
    const float* W  = rightSide ? Wr : Wl;
    const float* bb = rightSide ? br : bl;
    float* out      = rightSide ? xr : xl;

    float acc[2][4];
    #pragma unroll
    for (int i = 0; i < 2; i++)
        #pragma unroll
        for (int j = 0; j < 4; j++) acc[i][j] = 0.f;

    const float* xrow = xs + ng * 2 * 128;
    for (int k0 = 0; k0 < 128; k0 += 4) {
        float4 wv[4];
        #pragma unroll
        for (int kk = 0; kk < 4; kk++)
            wv[kk] = *(const float4*)(W + (size_t)(k0 + kk) * 32 + c);
        #pragma unroll
        for (int i = 0; i < 2; i++) {
            float4 xv = *(const float4*)(xrow + i * 128 + k0);
            float xvk[4] = {xv.x, xv.y, xv.z, xv.w};
            #pragma unroll
            for (int kk = 0; kk < 4; kk++) {
                acc[i][0] += xvk[kk] * wv[kk].x;
                acc[i][1] += xvk[kk] * wv[kk].y;
                acc[i][2] += xvk[kk] * wv[kk].z;
                acc[i][3] += xvk[kk] * wv[kk].w;
            }
        }
    }
    float4 bv = *(const float4*)(bb + c);
    #pragma unroll
    for (int i = 0; i < 2; i++) {
        int node = node0 + ng * 2 + i;
        if (node < N) {
            float4 o = make_float4(acc[i][0] + bv.x, acc[i][1] + bv.y,
                                   acc[i][2] + bv.z, acc[i][3] + bv.w);
            *(float4*)(out + (size_t)node * 32 + c) = o;
        }
    }
}

// ---------------- fused attention+aggregate, bf16 xl (layers 1-2, HC=128) ----
// 2-deep pipelined gathers per slot + defer-max online softmax.
__device__ __forceinline__ void unpack8(int4 rv, float* v) {
    unsigned u0 = (unsigned)rv.x, u1 = (unsigned)rv.y;
    unsigned u2 = (unsigned)rv.z, u3 = (unsigned)rv.w;
    v[0] = __uint_as_float(u0 << 16); v[1] = __uint_as_float(u0 & 0xFFFF0000u);
    v[2] = __uint_as_float(u1 << 16); v[3] = __uint_as_float(u1 & 0xFFFF0000u);
    v[4] = __uint_as_float(u2 << 16); v[5] = __uint_as_float(u2 & 0xFFFF0000u);
    v[6] = __uint_as_float(u3 << 16); v[7] = __uint_as_float(u3 & 0xFFFF0000u);
}

__global__ void k_fusedb(const int* __restrict__ row_off, const int* __restrict__ csr_src,
                         const unsigned short* __restrict__ xlb, const float* __restrict__ xr,
                         const float* __restrict__ att, const float* __restrict__ bias,
                         float* __restrict__ hout, int N) {
    constexpr int HC = 128, CPL = 8, GROUP = 8;  // C=64: 8 lanes/head
    int wid = (blockIdx.x * blockDim.x + threadIdx.x) >> 6;
    int lane = threadIdx.x & 63;
    if (wid >= N) return;
    int slot = lane >> 4;
    int j = lane & 15;
    int c0 = j * CPL;

    int p0 = row_off[wid], p1 = row_off[wid + 1];

    float xrv[CPL], attv[CPL];
    {
        float4 a = *(const float4*)(xr + (size_t)wid * HC + c0);
        float4 b = *(const float4*)(xr + (size_t)wid * HC + c0 + 4);
        xrv[0] = a.x; xrv[1] = a.y; xrv[2] = a.z; xrv[3] = a.w;
        xrv[4] = b.x; xrv[5] = b.y; xrv[6] = b.z; xrv[7] = b.w;
        float4 c = *(const float4*)(att + c0);
        float4 d = *(const float4*)(att + c0 + 4);
        attv[0] = c.x; attv[1] = c.y; attv[2] = c.z; attv[3] = c.w;
        attv[4] = d.x; attv[5] = d.y; attv[6] = d.z; attv[7] = d.w;
    }

    float m = -INFINITY, den = 0.f;
    float acc[CPL];
    #pragma unroll
    for (int q = 0; q < CPL; q++) acc[q] = 0.f;

    int p = p0 + slot;
    int s0 = (p < p1) ? csr_src[p] : 0;
    int s1 = (p + 4 < p1) ? csr_src[p + 4] : 0;
    while (p < p1) {
        int np = p + 8;
        int ns0 = (np < p1) ? csr_src[np] : 0;        // prefetch next pair
        int ns1 = (np + 4 < p1) ? csr_src[np + 4] : 0;
        bool has2 = (p + 4) < p1;
        int4 ra = *(const int4*)(xlb + (size_t)s0 * HC + c0);  // both gathers
        int4 rb = *(const int4*)(xlb + (size_t)s1 * HC + c0);  // in flight
        float xa[CPL], xb[CPL];
        unpack8(ra, xa);
        unpack8(rb, xb);
        float pa = 0.f, pb = 0.f;
        #pragma unroll
        for (int q = 0; q < CPL; q++) {
            float ta = xa[q] + xrv[q];
            float tb = xb[q] + xrv[q];
            pa = fmaf(fmaxf(ta, 0.2f * ta), attv[q], pa);
            pb = fmaf(fmaxf(tb, 0.2f * tb), attv[q], pb);
        }
        #pragma unroll
        for (int msk = 1; msk < GROUP; msk <<= 1) {
            pa += __shfl_xor(pa, msk, 64);
            pb += __shfl_xor(pb, msk, 64);
        }
        // defer-max: rescale only on big new max (exp(part-m) <= e^8 bounded)
        if (pa > m + 8.f) {
            float corr = __expf(m - pa);   // m=-inf -> 0
            den *= corr;
            #pragma unroll
            for (int q = 0; q < CPL; q++) acc[q] *= corr;
            m = pa;
        }
        float ea = __expf(pa - m);
        den += ea;
        #pragma unroll
        for (int q = 0; q < CPL; q++) acc[q] = fmaf(ea, xa[q], acc[q]);
        if (has2) {
            if (pb > m + 8.f) {
                float corr = __expf(m - pb);
                den *= corr;
                #pragma unroll
                for (int q = 0; q < CPL; q++) acc[q] *= corr;
                m = pb;
            }
            float eb = __expf(pb - m);
            den += eb;
            #pragma unroll
            for (int q = 0; q < CPL; q++) acc[q] = fmaf(eb, xb[q], acc[q]);
        }
        p = np; s0 = ns0; s1 = ns1;
    }
    float mAll = fmaxf(m, __shfl_xor(m, 16, 64));
    mAll = fmaxf(mAll, __shfl_xor(mAll, 32, 64));
    float scale = __expf(m - mAll);
    float dtot = den * scale;
    dtot += __shfl_xor(dtot, 16, 64);
    dtot += __shfl_xor(dtot, 32, 64);
    #pragma unroll
    for (int q = 0; q < CPL; q++) {
        float a = acc[q] * scale;
        a += __shfl_xor(a, 16, 64);
        a += __shfl_xor(a, 32, 64);
        acc[q] = a;
    }
    if (slot == 0) {
        float inv = 1.0f / (dtot + 1e-16f);
        #pragma unroll
        for (int q = 0; q < CPL; q++) {
            float v = acc[q] * inv + bias[c0 + q];
            hout[(size_t)wid * HC + c0 + q] = elu1(v);
        }
    }
}

// ---------------- fused attention+aggregate, fp32 (layer 3, HC=32) ----------
template <int CPL>
__device__ __forceinline__ void loadrow(const float* __restrict__ p, float* v) {
    if constexpr (CPL == 8) {
        float4 a = ((const float4*)p)[0];
        float4 b = ((const float4*)p)[1];
        v[0] = a.x; v[1] = a.y; v[2] = a.z; v[3] = a.w;
        v[4] = b.x; v[5] = b.y; v[6] = b.z; v[7] = b.w;
    } else {
        float2 a = ((const float2*)p)[0];
        v[0] = a.x; v[1] = a.y;
    }
}

template <int HC, int C>
__global__ void k_fused(const int* __restrict__ row_off, const int* __restrict__ csr_src,
                        const float* __restrict__ xl, const float* __restrict__ xr,
                        const float* __restrict__ att, const float* __restrict__ bias,
                        float* __restrict__ hout, int N) {
    constexpr int CPL = HC / 16;
    constexpr int GROUP = (16 * C) / HC;
    int wid = (blockIdx.x * blockDim.x + threadIdx.x) >> 6;
    int lane = threadIdx.x & 63;
    if (wid >= N) return;
    int slot = lane >> 4;
    int j = lane & 15;
    int c0 = j * CPL;

    int p0 = row_off[wid], p1 = row_off[wid + 1];

    float xrv[CPL], attv[CPL];
    loadrow<CPL>(xr + (size_t)wid * HC + c0, xrv);
    loadrow<CPL>(att + c0, attv);

    float m = -INFINITY, den = 0.f;
    float acc[CPL];
    #pragma unroll
    for (int q = 0; q < CPL; q++) acc[q] = 0.f;

    int p = p0 + slot;
    int s = (p < p1) ? csr_src[p] : 0;
    while (p < p1) {
        int pn = p + 4;
        int sn = (pn < p1) ? csr_src[pn] : 0;
        float xlv[CPL];
        loadrow<CPL>(xl + (size_t)s * HC + c0, xlv);
        float part = 0.f;
        #pragma unroll
        for (int q = 0; q < CPL; q++) {
            float t = xlv[q] + xrv[q];
            part = fmaf(fmaxf(t, 0.2f * t), attv[q], part);
        }
        #pragma unroll
        for (int msk = 1; msk < GROUP; msk <<= 1) part += __shfl_xor(part, msk, 64);
        if (part > m + 8.f) {
            float corr = __expf(m - part);
            den *= corr;
            #pragma unroll
            for (int q = 0; q < CPL; q++) acc[q] *= corr;
            m = part;
        }
        float ex = __expf(part - m);
        den += ex;
        #pragma unroll
        for (int q = 0; q < CPL; q++) acc[q] = fmaf(ex, xlv[q], acc[q]);
        p = pn; s = sn;
    }
    float mAll = fmaxf(m, __shfl_xor(m, 16, 64));
    mAll = fmaxf(mAll, __shfl_xor(mAll, 32, 64));
    float scale = __expf(m - mAll);
    float dtot = den * scale;
    dtot += __shfl_xor(dtot, 16, 64);
    dtot += __shfl_xor(dtot, 32, 64);
    #pragma unroll
    for (int q = 0; q < CPL; q++) {
        float a = acc[q] * scale;
        a += __shfl_xor(a, 16, 64);
        a += __shfl_xor(a, 32, 64);
        acc[q] = a;
    }
    if (slot == 0) {
        float inv = 1.0f / (dtot + 1e-16f);
        #pragma unroll
        for (int q = 0; q < CPL; q++) {
            float v = acc[q] * inv + bias[c0 + q];
            hout[(size_t)wid * HC + c0 + q] = elu1(v);
        }
    }
}

// ---------------- graph pooling (parallel, 2-stage) ----------------
__global__ void __launch_bounds__(256) k_pool_partial(
        const float* __restrict__ h, const int* __restrict__ batch, int N, int G,
        float* __restrict__ gsum, unsigned* __restrict__ gmax) {
    __shared__ float lsum[512];
    __shared__ unsigned lmax[512];
    int tid = threadIdx.x;
    for (int i = tid; i < G * 32; i += 256) { lsum[i] = 0.f; lmax[i] = 0u; }
    __syncthreads();
    int chunk = (N + gridDim.x - 1) / gridDim.x;
    int start = blockIdx.x * chunk;
    int end = min(N, start + chunk);
    int col = tid & 31, row = tid >> 5;
    int gc = -1; float ps = 0.f; unsigned pm = 0u;
    for (int i = start + row; i < end; i += 8) {
        int g = batch[i];
        if (g != gc) {
            if (gc >= 0) { atomicAdd(&lsum[gc * 32 + col], ps); atomicMax(&lmax[gc * 32 + col], pm); }
            gc = g; ps = 0.f; pm = 0u;
        }
        float v = h[(size_t)i * 32 + col];
        ps += v; pm = max(pm, f2ord(v));
    }
    if (gc >= 0) { atomicAdd(&lsum[gc * 32 + col], ps); atomicMax(&lmax[gc * 32 + col], pm); }
    __syncthreads();
    for (int i = tid; i < G * 32; i += 256) {
        if (lmax[i]) {
            atomicAdd(&gsum[i], lsum[i]);
            atomicMax(&gmax[i], lmax[i]);
        }
    }
}

__global__ void k_pool_final(const float* __restrict__ gsum, const unsigned* __restrict__ gmax,
                             const int* __restrict__ batch, int N, float* __restrict__ out) {
    int g = blockIdx.x;
    int t = threadIdx.x;
    __shared__ int s_cnt;
    if (t == 0) {
        int lo = 0, hi = N;
        while (lo < hi) { int m = (lo + hi) >> 1; if (batch[m] < g) lo = m + 1; else hi = m; }
        int a = lo;
        lo = a; hi = N;
        while (lo < hi) { int m = (lo + hi) >> 1; if (batch[m] < g + 1) lo = m + 1; else hi = m; }
        s_cnt = lo - a;
    }
    __syncthreads();
    if (t < 32) {
        out[g * 64 + t] = gsum[g * 32 + t] / (float)max(s_cnt, 1);
    } else {
        out[g * 64 + t] = ord2f(gmax[g * 32 + (t - 32)]);
    }
}

extern "C" void kernel_launch(void* const* d_in, const int* in_sizes, int n_in,
                              void* d_out, int out_size, void* d_ws, size_t ws_size,
                              hipStream_t stream) {
    const float* x      = (const float*)d_in[0];
    const int*   ei     = (const int*)d_in[1];
    const int*   batch  = (const int*)d_in[2];
    const float* Wl1 = (const float*)d_in[3],  *bl1 = (const float*)d_in[4];
    const float* Wr1 = (const float*)d_in[5],  *br1 = (const float*)d_in[6];
    const float* att1= (const float*)d_in[7],  *b1  = (const float*)d_in[8];
    const float* Wl2 = (const float*)d_in[9],  *bl2 = (const float*)d_in[10];
    const float* Wr2 = (const float*)d_in[11], *br2 = (const float*)d_in[12];
    const float* att2= (const float*)d_in[13], *b2  = (const float*)d_in[14];
    const float* Wl3 = (const float*)d_in[15], *bl3 = (const float*)d_in[16];
    const float* Wr3 = (const float*)d_in[17], *br3 = (const float*)d_in[18];
    const float* att3= (const float*)d_in[19], *b3  = (const float*)d_in[20];

    int N = in_sizes[0] / 8;
    int E = in_sizes[1] / 2;
    int G = out_size / 64;
    int Etot = E + N;
    int nb = (N + 1023) / 1024;   // scan blocks

    char* w = (char*)d_ws;
    auto carve = [&](size_t bytes) {
        void* p = (void*)w;
        w += (bytes + 255) & ~(size_t)255;
        return p;
    };
    int*            deg     = (int*)carve((size_t)N * 4);
    int*            row_off = (int*)carve((size_t)(N + 1) * 4);
    int*            cursor  = (int*)carve((size_t)N * 4);
    int*            part    = (int*)carve((size_t)N * 4);
    int*            bsum    = (int*)carve((size_t)nb * 4);
    int*            boff    = (int*)carve((size_t)nb * 4);
    int*            csr_src = (int*)carve((size_t)Etot * 4);
    float*          gsum    = (float*)carve((size_t)G * 32 * 4);
    unsigned*       gmax    = (unsigned*)carve((size_t)G * 32 * 4);
    unsigned short* xlb     = (unsigned short*)carve((size_t)N * 128 * 2);  // bf16 xl
    float*          bufA    = (float*)carve((size_t)N * 128 * 4);  // fp32 xl (layer 3)
    float*          bufB    = (float*)carve((size_t)N * 128 * 4);  // xr
    float*          bufC    = (float*)carve((size_t)N * 128 * 4);  // h (layer outputs)
    (void)ws_size; (void)n_in;

    // ---- CSR by dst (incl. self loops) + pool accumulator init ----
    k_zero_i32<<<(N + 255) / 256, 256, 0, stream>>>(deg, N);
    k_zero_i32<<<(2 * G * 32 + 255) / 256, 256, 0, stream>>>((int*)gsum, 2 * G * 32);
    k_hist<<<(Etot + 255) / 256, 256, 0, stream>>>(ei, E, N, deg);
    k_scan_blk<<<nb, 1024, 0, stream>>>(deg, N, part, bsum);
    k_scan_top<<<1, 64, 0, stream>>>(bsum, nb, boff, row_off, N);
    k_scan_add<<<nb, 1024, 0, stream>>>(part, boff, N, row_off, cursor);
    k_scatter<<<(Etot + 255) / 256, 256, 0, stream>>>(ei, E, N, cursor, csr_src);

    int grdLin = (N + 31) / 32;
    int grdFused = (N + 3) / 4;

    // ---- Layer 1: K=8 -> 128 (H=2,C=64), bf16 xl ----
    k_linear2b<8><<<grdLin, 256, 0, stream>>>(x, N, Wl1, bl1, Wr1, br1, xlb, bufB);
    k_fusedb<<<grdFused, 256, 0, stream>>>(row_off, csr_src, xlb, bufB, att1, b1, bufC, N);

    // ---- Layer 2: 128 -> 128, bf16 xl ----
    k_linear2b<128><<<grdLin, 256, 0, stream>>>(bufC, N, Wl2, bl2, Wr2, br2, xlb, bufB);
    k_fusedb<<<grdFused, 256, 0, stream>>>(row_off, csr_src, xlb, bufB, att2, b2, bufC, N);

    // ---- Layer 3: 128 -> 32 (H=1,C=32), all fp32 ----
    k_linear3<<<grdLin, 256, 0, stream>>>(bufC, N, Wl3, bl3, Wr3, br3, bufA, bufB);
    k_fused<32, 32><<<grdFused, 256, 0, stream>>>(row_off, csr_src, bufA, bufB, att3, b3, bufC, N);

    // ---- pooling ----
    k_pool_partial<<<256, 256, 0, stream>>>(bufC, batch, N, G, gsum, gmax);
    k_pool_final<<<G, 64, 0, stream>>>(gsum, gmax, batch, N, (float*)d_out);
}